// Round 6
// baseline (6426.408 us; speedup 1.0000x reference)
//
#include <hip/hip_runtime.h>
#include <math.h>

constexpr int SVEC = 576;    // N_CH * 64
constexpr int INF  = 2304;   // 4 * SVEC
constexpr int HID  = 256;
constexpr int OUTF = 1152;   // 2 * SVEC
constexpr int TS   = 20;
// red slot layout (line-spread buckets, 1 bucket = 1 cache line):
//   r[b] at b*16, d[b] at 512+b*16, q[b] at 1024+b*16, b in 0..31
constexpr int RSL  = 1536;   // floats per step slot (6 KB)

// ---------- helpers ----------------------------------------------------------
__device__ __forceinline__ ushort f2bf(float f) {    // RNE f32->bf16
    union { float f; unsigned u; } a; a.f = f;
    unsigned r = a.u + 0x7fff + ((a.u >> 16) & 1);
    return (ushort)(r >> 16);
}
__device__ __forceinline__ float bf2f(ushort b) {
    union { unsigned u; float f; } a; a.u = ((unsigned)b) << 16;
    return a.f;
}

// LDS-only barrier: orders ds ops across the block WITHOUT draining vmcnt.
__device__ __forceinline__ void bar_lgkm() {
    asm volatile("s_waitcnt lgkmcnt(0)\n\ts_barrier" ::: "memory");
}

typedef short  s16x8 __attribute__((ext_vector_type(8)));
typedef float  f32x4 __attribute__((ext_vector_type(4)));

// ---------- init: Sb(bf16) = [x|p|y|z] all = [noisy, 0...] -------------------
__global__ __launch_bounds__(256) void k_init(ushort* __restrict__ Sb,
                                              const float4* __restrict__ noisy4,
                                              int tot8) {
    int i = blockIdx.x * 256 + threadIdx.x;
    if (i >= tot8) return;
    int sample = i / 288;
    int j = i - sample * 288;
    int jc = j % 72;
    s16x8 o = (s16x8){0,0,0,0,0,0,0,0};
    if (jc < 8) {
        float4 a = noisy4[sample * 16 + jc * 2];
        float4 b = noisy4[sample * 16 + jc * 2 + 1];
        ushort* u = (ushort*)&o;
        u[0]=f2bf(a.x); u[1]=f2bf(a.y); u[2]=f2bf(a.z); u[3]=f2bf(a.w);
        u[4]=f2bf(b.x); u[5]=f2bf(b.y); u[6]=f2bf(b.z); u[7]=f2bf(b.w);
    }
    *(s16x8*)&Sb[(size_t)i * 8] = o;
}

__global__ __launch_bounds__(128) void k_zero(float* __restrict__ p, int n) {
    int i = blockIdx.x * 128 + threadIdx.x;
    if (i < n) p[i] = 0.f;
}

// ---------- fragment-linear weight repack (unchanged, verified) --------------
__global__ __launch_bounds__(256) void k_wf(const float* __restrict__ W,
                                            ushort* __restrict__ Wf,
                                            int KS, int stride, int perm,
                                            int total) {
    int o = blockIdx.x * 256 + threadIdx.x;
    if (o >= total) return;
    int e = o & 7;
    int lane = (o >> 3) & 63;
    int rem = o >> 9;
    int s = rem % KS, f = rem / KS;
    int quad = lane >> 4, lm = lane & 15;
    int kp = s * 32 + quad * 8 + e;
    int korig = perm ? (kp & 3) * 576 + (kp >> 2) : kp;
    int n = f * 16 + lm;
    Wf[o] = f2bf(W[(size_t)korig * stride + n]);
}

// ---------- FBS state: x,p,y,z only (u,v arrive via LDS slabs) ---------------
struct FbsXZ { s16x8 x8, p8, y8, z8; };

__device__ __forceinline__ void fbs_load2(FbsXZ& f, const ushort* __restrict__ Sb,
                                          size_t sb) {
    f.x8 = *(const s16x8*)(Sb + sb);
    f.p8 = *(const s16x8*)(Sb + sb + SVEC);
    f.y8 = *(const s16x8*)(Sb + sb + 2 * SVEC);
    f.z8 = *(const s16x8*)(Sb + sb + 3 * SVEC);
}

// uv slab write: chunk C needs u-frags 4C..4C+3 and v-frags 36+4C..+3.
// Frag f is held by wave f/9 (pj = f%9) -> all register indices static.
// Slab layout: u [row][64 cols] at 0, v at +4096 (ushorts).
template<int C>
__device__ __forceinline__ void slabw(const uint (&uvp)[72], ushort* slab,
                                      int wave, int quad, int lm) {
    #pragma unroll
    for (int s = 0; s < 8; ++s) {
        const int f  = (s < 4) ? (4 * C + s) : (36 + 4 * C + (s - 4));
        const int W  = f / 9, pj = f % 9;
        if (wave == W) {
            ushort* base = slab + ((s < 4) ? 0 : 4096) + (s & 3) * 16 + lm;
            #pragma unroll
            for (int i = 0; i < 4; ++i)
                #pragma unroll
                for (int h = 0; h < 2; ++h) {
                    uint w = uvp[(pj * 4 + i) * 2 + h];
                    int row0 = i * 16 + quad * 4 + h * 2;
                    base[row0 * 64]       = (ushort)(w & 0xffff);
                    base[(row0 + 1) * 64] = (ushort)(w >> 16);
                }
        }
    }
}

// FBS math identical to verified kernel; u,v read from slab (written from uvp,
// values are exactly the old f2bf(cv) bf16s). LAST: write p_out f32, skip Sb/A.
template<bool LAST>
__device__ __forceinline__ void finish2(ushort* __restrict__ Sb, size_t sb,
                                        ushort* __restrict__ Abuf,
                                        const ushort* __restrict__ slab,
                                        float* __restrict__ pout,
                                        int frow, int fjg, float an, float al,
                                        FbsXZ& f, float& r, float& d) {
    s16x8 u8 = *(const s16x8*)(slab + frow * 64 + fjg * 8);
    s16x8 v8 = *(const s16x8*)(slab + 4096 + frow * 64 + fjg * 8);
    s16x8 xo, po, yo, zo;
    float prf[8];
    const ushort* X = (const ushort*)&f.x8; const ushort* P = (const ushort*)&f.p8;
    const ushort* Y = (const ushort*)&f.y8; const ushort* Z = (const ushort*)&f.z8;
    const ushort* U = (const ushort*)&u8;   const ushort* V = (const ushort*)&v8;
    ushort* XO = (ushort*)&xo; ushort* PO = (ushort*)&po;
    ushort* YO = (ushort*)&yo; ushort* ZO = (ushort*)&zo;
    #pragma unroll
    for (int cc = 0; cc < 8; ++cc) {
        float x = bf2f(X[cc]), p = bf2f(P[cc]);
        float yv = bf2f(Y[cc]), zv = bf2f(Z[cc]);
        float u = al * bf2f(U[cc]), v = al * bf2f(V[cc]);
        float y  = x + an * (yv - x) + u;
        float dz = an * (zv - p);
        float z  = x + an * (p - x) + dz + u + v;
        float zm = z - y;
        float t  = fabsf(zm) - 0.1f;
        float pr = (t > 0.f) ? copysignf(t, zm) : 0.f;
        float xn = x + (pr - z) + dz;
        XO[cc] = f2bf(xn); PO[cc] = f2bf(pr); YO[cc] = f2bf(y); ZO[cc] = f2bf(z);
        if (LAST) prf[cc] = pr;
        float e1 = pr - y; r += e1 * e1;
        if (!LAST) { float e2 = xn - z; d += e2 * e2; }
    }
    if constexpr (LAST) {
        *(float4*)(pout)     = make_float4(prf[0], prf[1], prf[2], prf[3]);
        *(float4*)(pout + 4) = make_float4(prf[4], prf[5], prf[6], prf[7]);
    } else {
        *(s16x8*)(Sb + sb)            = xo;
        *(s16x8*)(Sb + sb + SVEC)     = po;
        *(s16x8*)(Sb + sb + 2 * SVEC) = yo;
        *(s16x8*)(Sb + sb + 3 * SVEC) = zo;
        #pragma unroll
        for (int cc = 0; cc < 4; ++cc) {
            s16x8 w; ushort* W = (ushort*)&w;
            #pragma unroll
            for (int t = 0; t < 2; ++t) {
                int jj = cc * 2 + t;
                W[t*4+0] = XO[jj]; W[t*4+1] = PO[jj];
                W[t*4+2] = YO[jj]; W[t*4+3] = ZO[jj];
            }
            int ch = (4 * fjg + cc) ^ (frow & 7);
            *(s16x8*)&Abuf[frow * 256 + ch * 8] = w;
        }
    }
}

// one phase-1 iteration (all slot/register indices compile-time via template C)
template<int C>
__device__ __forceinline__ void ph1_iter(
    ushort (&As)[2][64 * 256], ushort (&Sl)[3][8192],
    const s16x8* __restrict__ Wf1v, s16x8 (&b1)[4][2], f32x4 (&acc)[4][2],
    const uint (&uvp)[72], ushort* __restrict__ Sb, size_t srow,
    int wave, int lane, int lm, int quad, int frow, int fjg,
    float an, float al, FbsXZ& fsx, float& r, float& d) {
    const ushort* Ab = As[C & 1];
    #pragma unroll
    for (int kk = 0; kk < 8; ++kk) {
        if (C * 8 + kk + 3 < 72) {
            #pragma unroll
            for (int j = 0; j < 2; ++j)
                b1[(kk + 3) & 3][j] =
                    Wf1v[((wave * 2 + j) * 72 + C * 8 + kk + 3) * 64 + lane];
        }
        s16x8 af[4];
        #pragma unroll
        for (int i = 0; i < 4; ++i)
            af[i] = *(const s16x8*)&Ab[(i * 16 + lm) * 256 +
                     ((((kk << 2) + quad) ^ (lm & 7)) << 3)];
        #pragma unroll
        for (int i = 0; i < 4; ++i)
            #pragma unroll
            for (int j = 0; j < 2; ++j)
                acc[i][j] = __builtin_amdgcn_mfma_f32_16x16x32_bf16(
                    af[i], b1[kk & 3][j], acc[i][j], 0, 0, 0);
    }
    if constexpr (C < 8)
        finish2<false>(Sb, srow + (size_t)(C + 1) * 64, As[(C + 1) & 1],
                       Sl[(C + 1) % 3], nullptr, frow, fjg, an, al, fsx, r, d);
    if constexpr (C < 6) {
        fbs_load2(fsx, Sb, srow + (size_t)(C + 3) * 64);
        slabw<C + 3>(uvp, Sl[(C + 3) % 3], wave, quad, lm);
    }
    if constexpr (C < 8) bar_lgkm();
}

template<int CC>
__device__ __forceinline__ void tail_iter(
    ushort (&Sl)[3][8192], const uint (&uvp)[72],
    ushort* __restrict__ Sb, size_t srow, float* __restrict__ prow,
    int wave, int quad, int lm, int frow, int fjg,
    float an, float al, FbsXZ& fsx, float& r, float& d) {
    finish2<true>(Sb, srow + (size_t)CC * 64, nullptr, Sl[CC % 3],
                  prow + CC * 64, frow, fjg, an, al, fsx, r, d);
    if constexpr (CC <= 6) {
        fbs_load2(fsx, Sb, srow + (size_t)(CC + 2) * 64);
        slabw<CC + 2>(uvp, Sl[(CC + 2) % 3], wave, quad, lm);
    }
    if constexpr (CC < 8) bar_lgkm();
}

// device-scope sense-reversing grid barrier (grid == co-resident: 256 blocks,
// 1/CU). gen read BEFORE arrive -> release can't complete without all arrivals.
__device__ __forceinline__ void gridbar(int* cnt, int* gen, int nblk) {
    __syncthreads();
    if (threadIdx.x == 0) {
        __threadfence();
        int g = __hip_atomic_load(gen, __ATOMIC_RELAXED, __HIP_MEMORY_SCOPE_AGENT);
        int v = __hip_atomic_fetch_add(cnt, 1, __ATOMIC_ACQ_REL, __HIP_MEMORY_SCOPE_AGENT);
        if (v == nblk - 1) {
            __hip_atomic_store(cnt, 0, __ATOMIC_RELAXED, __HIP_MEMORY_SCOPE_AGENT);
            __hip_atomic_fetch_add(gen, 1, __ATOMIC_RELEASE, __HIP_MEMORY_SCOPE_AGENT);
        } else {
            while (__hip_atomic_load(gen, __ATOMIC_ACQUIRE,
                                     __HIP_MEMORY_SCOPE_AGENT) == g)
                __builtin_amdgcn_s_sleep(16);
        }
        __threadfence();
    }
    __syncthreads();
}

// ---------- persistent all-steps kernel --------------------------------------
// 1 block = 64 samples FOREVER (grid 256 = 1/CU). uv lives in registers
// (72 VGPR packed bf16) across steps; exchanged to FBS consumers via 3-slot
// LDS slab ring. Step n+1's chunk0/1 Sb loads issue BEFORE the grid barrier.
// Step 19: FBS-only, writes p_out f32 directly, no Sb writeback, no GEMMs.
__global__ __launch_bounds__(512, 2) void k_persist(
    ushort* __restrict__ Sb,
    const ushort* __restrict__ Wf1, const ushort* __restrict__ Wf2,
    const ushort* __restrict__ Wf3,
    const float* __restrict__ b1v, const float* __restrict__ b2v,
    const float* __restrict__ b3v,
    float* __restrict__ red, int* __restrict__ bsync,
    float* __restrict__ pout, int nblk) {
    __shared__ ushort As[2][64 * 256];   // 64 KB: A dbuf / h1 / h2
    __shared__ ushort Sl[3][8192];       // 48 KB: uv slab ring (u|v 4096 each)
    const int tid  = threadIdx.x;
    const int wave = tid >> 6, lane = tid & 63;
    const int lm = lane & 15, quad = lane >> 4;
    const int sample0 = blockIdx.x * 64;
    const int frow = tid >> 3, fjg = tid & 7;
    const s16x8* Wf1v = (const s16x8*)Wf1;
    const s16x8* Wf2v = (const s16x8*)Wf2;
    const s16x8* Wf3v = (const s16x8*)Wf3;
    const size_t srow = (size_t)(sample0 + frow) * INF + fjg * 8;
    float* prow = pout + (size_t)(sample0 + frow) * SVEC + fjg * 8;

    uint uvp[72];
    #pragma unroll
    for (int i = 0; i < 72; ++i) uvp[i] = 0u;

    FbsXZ fs0, fs1;
    fbs_load2(fs0, Sb, srow);
    fbs_load2(fs1, Sb, srow + 64);

    #pragma unroll 1
    for (int n = 0; n < TS - 1; ++n) {
        const float an = (float)n / ((float)n + 3.0f);
        const float* redprev = red + (size_t)n * RSL;
        float* redcur = red + (size_t)(n + 1) * RSL;
        float av = (lane < 32) ? redprev[512 + lane * 16]
                               : redprev[1024 + (lane - 32) * 16];
        #pragma unroll
        for (int off = 16; off > 0; off >>= 1) av += __shfl_down(av, off);
        const float dsum = __shfl(av, 0), qsum = __shfl(av, 32);
        const float al = sqrtf(fminf(0.99f * fmaxf(dsum, 0.f) /
                                     (1.5f * qsum + 1e-12f), 1.f));

        s16x8 b1[4][2];
        #pragma unroll
        for (int t = 0; t < 3; ++t)
            #pragma unroll
            for (int j = 0; j < 2; ++j)
                b1[t][j] = Wf1v[((wave * 2 + j) * 72 + t) * 64 + lane];

        float r = 0.f, d = 0.f;
        slabw<0>(uvp, Sl[0], wave, quad, lm);
        slabw<1>(uvp, Sl[1], wave, quad, lm);
        bar_lgkm();
        finish2<false>(Sb, srow, As[0], Sl[0], nullptr, frow, fjg, an, al,
                       fs0, r, d);
        fbs_load2(fs0, Sb, srow + 128);
        slabw<2>(uvp, Sl[2], wave, quad, lm);
        bar_lgkm();

        f32x4 acc[4][2];
        #pragma unroll
        for (int i = 0; i < 4; ++i)
            #pragma unroll
            for (int j = 0; j < 2; ++j) acc[i][j] = (f32x4){0.f, 0.f, 0.f, 0.f};

        ph1_iter<0>(As, Sl, Wf1v, b1, acc, uvp, Sb, srow, wave, lane, lm, quad, frow, fjg, an, al, fs1, r, d);
        ph1_iter<1>(As, Sl, Wf1v, b1, acc, uvp, Sb, srow, wave, lane, lm, quad, frow, fjg, an, al, fs0, r, d);
        ph1_iter<2>(As, Sl, Wf1v, b1, acc, uvp, Sb, srow, wave, lane, lm, quad, frow, fjg, an, al, fs1, r, d);
        ph1_iter<3>(As, Sl, Wf1v, b1, acc, uvp, Sb, srow, wave, lane, lm, quad, frow, fjg, an, al, fs0, r, d);
        ph1_iter<4>(As, Sl, Wf1v, b1, acc, uvp, Sb, srow, wave, lane, lm, quad, frow, fjg, an, al, fs1, r, d);
        ph1_iter<5>(As, Sl, Wf1v, b1, acc, uvp, Sb, srow, wave, lane, lm, quad, frow, fjg, an, al, fs0, r, d);
        ph1_iter<6>(As, Sl, Wf1v, b1, acc, uvp, Sb, srow, wave, lane, lm, quad, frow, fjg, an, al, fs1, r, d);
        ph1_iter<7>(As, Sl, Wf1v, b1, acc, uvp, Sb, srow, wave, lane, lm, quad, frow, fjg, an, al, fs0, r, d);
        ph1_iter<8>(As, Sl, Wf1v, b1, acc, uvp, Sb, srow, wave, lane, lm, quad, frow, fjg, an, al, fs0, r, d);

        #pragma unroll
        for (int off = 32; off > 0; off >>= 1) {
            r += __shfl_down(r, off);
            d += __shfl_down(d, off);
        }
        if (lane == 0) {
            int bk = ((blockIdx.x << 3) | wave) & 31;
            atomicAdd(&redcur[bk * 16],       r);
            atomicAdd(&redcur[512 + bk * 16], d);
        }

        // ---- h1 = relu(acc + b1) -> As[1] ----
        ushort* h1l = As[1];
        float bb1[2];
        #pragma unroll
        for (int j = 0; j < 2; ++j) bb1[j] = b1v[wave * 32 + j * 16 + lm];
        #pragma unroll
        for (int i = 0; i < 4; ++i)
            #pragma unroll
            for (int j = 0; j < 2; ++j)
                #pragma unroll
                for (int rr = 0; rr < 4; ++rr) {
                    int row = i * 16 + quad * 4 + rr;
                    int col = wave * 32 + j * 16 + lm;
                    float cv = fmaxf(acc[i][j][rr] + bb1[j], 0.f);
                    h1l[row * 256 + ((((col >> 3) ^ (row & 7)) << 3) | (col & 7))] = f2bf(cv);
                }
        s16x8 b2[4][2];
        #pragma unroll
        for (int t = 0; t < 3; ++t)
            #pragma unroll
            for (int j = 0; j < 2; ++j)
                b2[t][j] = Wf2v[((wave * 2 + j) * 8 + t) * 64 + lane];
        bar_lgkm();

        // ---- GEMM2 ----
        f32x4 a2[4][2];
        #pragma unroll
        for (int i = 0; i < 4; ++i)
            #pragma unroll
            for (int j = 0; j < 2; ++j) a2[i][j] = (f32x4){0.f, 0.f, 0.f, 0.f};
        #pragma unroll
        for (int kk = 0; kk < 8; ++kk) {
            if (kk < 5) {
                #pragma unroll
                for (int j = 0; j < 2; ++j)
                    b2[(kk + 3) & 3][j] = Wf2v[((wave * 2 + j) * 8 + kk + 3) * 64 + lane];
            }
            s16x8 af[4];
            #pragma unroll
            for (int i = 0; i < 4; ++i)
                af[i] = *(const s16x8*)&h1l[(i * 16 + lm) * 256 +
                         ((((kk << 2) + quad) ^ (lm & 7)) << 3)];
            #pragma unroll
            for (int i = 0; i < 4; ++i)
                #pragma unroll
                for (int j = 0; j < 2; ++j)
                    a2[i][j] = __builtin_amdgcn_mfma_f32_16x16x32_bf16(
                        af[i], b2[kk & 3][j], a2[i][j], 0, 0, 0);
        }
        ushort* h2l = As[0];
        float bb2[2];
        #pragma unroll
        for (int j = 0; j < 2; ++j) bb2[j] = b2v[wave * 32 + j * 16 + lm];
        #pragma unroll
        for (int i = 0; i < 4; ++i)
            #pragma unroll
            for (int j = 0; j < 2; ++j)
                #pragma unroll
                for (int rr = 0; rr < 4; ++rr) {
                    int row = i * 16 + quad * 4 + rr;
                    int col = wave * 32 + j * 16 + lm;
                    float cv = fmaxf(a2[i][j][rr] + bb2[j], 0.f);
                    h2l[row * 256 + ((((col >> 3) ^ (row & 7)) << 3) | (col & 7))] = f2bf(cv);
                }
        s16x8 b3[4][3];
        #pragma unroll
        for (int t = 0; t < 3; ++t)
            #pragma unroll
            for (int jj = 0; jj < 3; ++jj)
                b3[t][jj] = Wf3v[((wave * 9 + jj) * 8 + t) * 64 + lane];
        bar_lgkm();

        // ---- GEMM3 -> uvp (registers) + q ----
        float q = 0.f;
        f32x4 a3[3][4];
        #pragma unroll
        for (int t = 0; t < 24; ++t) {
            const int p = t >> 3, kk = t & 7;
            if (t < 21) {
                const int tp = (t + 3) >> 3, tk = (t + 3) & 7;
                #pragma unroll
                for (int jj = 0; jj < 3; ++jj)
                    b3[(t + 3) & 3][jj] =
                        Wf3v[((wave * 9 + tp * 3 + jj) * 8 + tk) * 64 + lane];
            }
            if (kk == 0) {
                #pragma unroll
                for (int jj = 0; jj < 3; ++jj)
                    #pragma unroll
                    for (int i = 0; i < 4; ++i) a3[jj][i] = (f32x4){0.f,0.f,0.f,0.f};
            }
            s16x8 af[4];
            #pragma unroll
            for (int i = 0; i < 4; ++i)
                af[i] = *(const s16x8*)&h2l[(i * 16 + lm) * 256 +
                         ((((kk << 2) + quad) ^ (lm & 7)) << 3)];
            #pragma unroll
            for (int jj = 0; jj < 3; ++jj)
                #pragma unroll
                for (int i = 0; i < 4; ++i)
                    a3[jj][i] = __builtin_amdgcn_mfma_f32_16x16x32_bf16(
                        af[i], b3[t & 3][jj], a3[jj][i], 0, 0, 0);
            if (kk == 7) {
                #pragma unroll
                for (int jj = 0; jj < 3; ++jj) {
                    int col = (wave * 9 + p * 3 + jj) * 16 + lm;
                    float bb = b3v[col];
                    #pragma unroll
                    for (int i = 0; i < 4; ++i) {
                        float c0 = a3[jj][i][0] + bb, c1 = a3[jj][i][1] + bb;
                        float c2 = a3[jj][i][2] + bb, c3 = a3[jj][i][3] + bb;
                        q += c0*c0 + c1*c1 + c2*c2 + c3*c3;
                        int ub = ((p * 3 + jj) * 4 + i) * 2;
                        uvp[ub]     = (uint)f2bf(c0) | ((uint)f2bf(c1) << 16);
                        uvp[ub + 1] = (uint)f2bf(c2) | ((uint)f2bf(c3) << 16);
                    }
                }
            }
        }
        #pragma unroll
        for (int off = 32; off > 0; off >>= 1) q += __shfl_down(q, off);
        if (lane == 0)
            atomicAdd(&redcur[1024 + (((blockIdx.x << 3) | wave) & 31) * 16], q);

        // next-step chunk0/1 prefetch (own rows, written early this step;
        // in-order vmcnt retirement guarantees those stores completed)
        fbs_load2(fs0, Sb, srow);
        fbs_load2(fs1, Sb, srow + 64);
        gridbar(bsync, bsync + 16, nblk);
    }

    // ---- step 19: FBS-only; p_out f32 direct; r only ----
    {
        const float an = (float)(TS - 1) / ((float)(TS - 1) + 3.0f);
        const float* redprev = red + (size_t)(TS - 1) * RSL;
        float* redcur = red + (size_t)TS * RSL;
        float av = (lane < 32) ? redprev[512 + lane * 16]
                               : redprev[1024 + (lane - 32) * 16];
        #pragma unroll
        for (int off = 16; off > 0; off >>= 1) av += __shfl_down(av, off);
        const float dsum = __shfl(av, 0), qsum = __shfl(av, 32);
        const float al = sqrtf(fminf(0.99f * fmaxf(dsum, 0.f) /
                                     (1.5f * qsum + 1e-12f), 1.f));
        float r = 0.f, d = 0.f;
        slabw<0>(uvp, Sl[0], wave, quad, lm);
        slabw<1>(uvp, Sl[1], wave, quad, lm);
        bar_lgkm();
        finish2<true>(Sb, srow, nullptr, Sl[0], prow, frow, fjg, an, al, fs0, r, d);
        fbs_load2(fs0, Sb, srow + 128);
        slabw<2>(uvp, Sl[2], wave, quad, lm);
        bar_lgkm();
        tail_iter<1>(Sl, uvp, Sb, srow, prow, wave, quad, lm, frow, fjg, an, al, fs1, r, d);
        tail_iter<2>(Sl, uvp, Sb, srow, prow, wave, quad, lm, frow, fjg, an, al, fs0, r, d);
        tail_iter<3>(Sl, uvp, Sb, srow, prow, wave, quad, lm, frow, fjg, an, al, fs1, r, d);
        tail_iter<4>(Sl, uvp, Sb, srow, prow, wave, quad, lm, frow, fjg, an, al, fs0, r, d);
        tail_iter<5>(Sl, uvp, Sb, srow, prow, wave, quad, lm, frow, fjg, an, al, fs1, r, d);
        tail_iter<6>(Sl, uvp, Sb, srow, prow, wave, quad, lm, frow, fjg, an, al, fs0, r, d);
        tail_iter<7>(Sl, uvp, Sb, srow, prow, wave, quad, lm, frow, fjg, an, al, fs1, r, d);
        tail_iter<8>(Sl, uvp, Sb, srow, prow, wave, quad, lm, frow, fjg, an, al, fs0, r, d);
        #pragma unroll
        for (int off = 32; off > 0; off >>= 1) r += __shfl_down(r, off);
        if (lane == 0)
            atomicAdd(&redcur[(((blockIdx.x << 3) | wave) & 31) * 16], r);
    }
}

// ---------- residuals only (p_out already written by k_persist) --------------
__global__ __launch_bounds__(64) void k_res(const float* __restrict__ red,
                                            float* __restrict__ res_out) {
    int t = threadIdx.x;
    if (t >= TS) return;
    const float* rb = red + (size_t)(t + 1) * RSL;
    float s = 0.f;
    #pragma unroll
    for (int c = 0; c < 32; ++c) s += rb[c * 16];
    res_out[t] = sqrtf(s + 1e-12f);
}

extern "C" void kernel_launch(void* const* d_in, const int* in_sizes, int n_in,
                              void* d_out, int out_size, void* d_ws, size_t ws_size,
                              hipStream_t stream) {
    const float* noisy = (const float*)d_in[0];
    const float* W1 = (const float*)d_in[1];
    const float* b1 = (const float*)d_in[2];
    const float* W2 = (const float*)d_in[3];
    const float* b2 = (const float*)d_in[4];
    const float* W3 = (const float*)d_in[5];
    const float* b3 = (const float*)d_in[6];
    const int B = in_sizes[0] / 64;   // 16384

    // workspace: Sb + frag-linear weights + red slots + barrier ints (~78 MB)
    ushort* Sb  = (ushort*)d_ws;                        // [B,2304] bf16
    ushort* Wf1 = Sb + (size_t)B * INF;                 // 16*72*512 frag-linear
    ushort* Wf2 = Wf1 + (size_t)HID * INF;              // 16*8*512
    ushort* Wf3 = Wf2 + (size_t)HID * HID;              // 72*8*512
    float*  red = (float*)((((uintptr_t)(Wf3 + (size_t)OUTF * HID)) + 63) &
                           ~(uintptr_t)63);
    int*    bsync = (int*)(red + 21 * RSL);             // cnt @ +0, gen @ +16

    float* p_out   = (float*)d_out;                     // [B,576]
    float* res_out = p_out + (size_t)B * SVEC;          // [20]

    const int tot8S = B * 288;

    k_init<<<(tot8S + 255) / 256, 256, 0, stream>>>(Sb, (const float4*)noisy, tot8S);
    k_zero<<<(21 * RSL + 64 + 127) / 128, 128, 0, stream>>>(red, 21 * RSL + 64);
    k_wf<<<(HID * INF + 255) / 256, 256, 0, stream>>>(W1, Wf1, 72, HID, 1, HID * INF);
    k_wf<<<(HID * HID + 255) / 256, 256, 0, stream>>>(W2, Wf2, 8, HID, 0, HID * HID);
    k_wf<<<(OUTF * HID + 255) / 256, 256, 0, stream>>>(W3, Wf3, 8, OUTF, 0, OUTF * HID);

    k_persist<<<B / 64, 512, 0, stream>>>(Sb, Wf1, Wf2, Wf3, b1, b2, b3,
                                          red, bsync, p_out, B / 64);
    k_res<<<1, 64, 0, stream>>>(red, res_out);
}

// Round 8
// 1471.167 us; speedup vs baseline: 4.3682x; 4.3682x over previous
//
#include <hip/hip_runtime.h>
#include <math.h>

constexpr int SVEC = 576;    // N_CH * 64
constexpr int INF  = 2304;   // 4 * SVEC
constexpr int HID  = 256;
constexpr int OUTF = 1152;   // 2 * SVEC
constexpr int TS   = 20;
// red slot layout (line-spread buckets, 1 bucket = 1 cache line):
//   r[b] at b*16, d[b] at 512+b*16, q[b] at 1024+b*16, b in 0..31
constexpr int RSL  = 1536;   // floats per step slot (6 KB)

// ---------- helpers ----------------------------------------------------------
__device__ __forceinline__ ushort f2bf(float f) {    // RNE f32->bf16
    union { float f; unsigned u; } a; a.f = f;
    unsigned r = a.u + 0x7fff + ((a.u >> 16) & 1);
    return (ushort)(r >> 16);
}
__device__ __forceinline__ float bf2f(ushort b) {
    union { unsigned u; float f; } a; a.u = ((unsigned)b) << 16;
    return a.f;
}

// LDS-only barrier: orders ds ops across the block WITHOUT draining vmcnt.
// Cross-thread data in this kernel flows only through LDS; global rows are
// thread-private within a step.
__device__ __forceinline__ void bar_lgkm() {
    asm volatile("s_waitcnt lgkmcnt(0)\n\ts_barrier" ::: "memory");
}

typedef short  s16x8 __attribute__((ext_vector_type(8)));
typedef short  s16x4 __attribute__((ext_vector_type(4)));
typedef float  f32x4 __attribute__((ext_vector_type(4)));

// ---------- init: Sb(bf16) = [x|p|y|z] all = [noisy, 0...] -------------------
__global__ __launch_bounds__(256) void k_init(ushort* __restrict__ Sb,
                                              const float4* __restrict__ noisy4,
                                              int tot8) {
    int i = blockIdx.x * 256 + threadIdx.x;
    if (i >= tot8) return;
    int sample = i / 288;
    int j = i - sample * 288;
    int jc = j % 72;
    s16x8 o = (s16x8){0,0,0,0,0,0,0,0};
    if (jc < 8) {
        float4 a = noisy4[sample * 16 + jc * 2];
        float4 b = noisy4[sample * 16 + jc * 2 + 1];
        ushort* u = (ushort*)&o;
        u[0]=f2bf(a.x); u[1]=f2bf(a.y); u[2]=f2bf(a.z); u[3]=f2bf(a.w);
        u[4]=f2bf(b.x); u[5]=f2bf(b.y); u[6]=f2bf(b.z); u[7]=f2bf(b.w);
    }
    *(s16x8*)&Sb[(size_t)i * 8] = o;
}

__global__ __launch_bounds__(128) void k_zero(float* __restrict__ p, int n) {
    int i = blockIdx.x * 128 + threadIdx.x;
    if (i < n) p[i] = 0.f;
}

// ---------- fragment-linear weight repack (unchanged, verified) --------------
__global__ __launch_bounds__(256) void k_wf(const float* __restrict__ W,
                                            ushort* __restrict__ Wf,
                                            int KS, int stride, int perm,
                                            int total) {
    int o = blockIdx.x * 256 + threadIdx.x;
    if (o >= total) return;
    int e = o & 7;
    int lane = (o >> 3) & 63;
    int rem = o >> 9;
    int s = rem % KS, f = rem / KS;
    int quad = lane >> 4, lm = lane & 15;
    int kp = s * 32 + quad * 8 + e;
    int korig = perm ? (kp & 3) * 576 + (kp >> 2) : kp;
    int n = f * 16 + lm;
    Wf[o] = f2bf(W[(size_t)korig * stride + n]);
}

// ---------- FBS pieces (4 elems/thread; 1024-thread blocks, 64 rows) ---------
struct FbsReg { s16x4 x4, p4, y4, z4, u4, v4; };

__device__ __forceinline__ void fbs_load(const ushort* __restrict__ Sb,
                                         const ushort* __restrict__ uv,
                                         size_t sb, size_t ub, FbsReg& f) {
    f.x4 = *(const s16x4*)(Sb + sb);
    f.p4 = *(const s16x4*)(Sb + sb + SVEC);
    f.y4 = *(const s16x4*)(Sb + sb + 2 * SVEC);
    f.z4 = *(const s16x4*)(Sb + sb + 3 * SVEC);
    f.u4 = *(const s16x4*)(uv + ub);
    f.v4 = *(const s16x4*)(uv + ub + SVEC);
}

// FBS math identical to the verified kernels (R3's 4-elem variant, passed).
__device__ __forceinline__ void fbs_finish(ushort* __restrict__ Sb, size_t sb,
                                           ushort* __restrict__ buf,
                                           int frow, int fjg,
                                           float an, float al,
                                           FbsReg& f, float& r, float& d) {
    s16x4 xo, po, yo, zo;
    const ushort* X = (const ushort*)&f.x4; const ushort* P = (const ushort*)&f.p4;
    const ushort* Y = (const ushort*)&f.y4; const ushort* Z = (const ushort*)&f.z4;
    const ushort* U = (const ushort*)&f.u4; const ushort* V = (const ushort*)&f.v4;
    ushort* XO = (ushort*)&xo; ushort* PO = (ushort*)&po;
    ushort* YO = (ushort*)&yo; ushort* ZO = (ushort*)&zo;
    #pragma unroll
    for (int cc = 0; cc < 4; ++cc) {
        float x = bf2f(X[cc]), p = bf2f(P[cc]);
        float yv = bf2f(Y[cc]), zv = bf2f(Z[cc]);
        float u = al * bf2f(U[cc]), v = al * bf2f(V[cc]);
        float y  = x + an * (yv - x) + u;
        float dz = an * (zv - p);
        float z  = x + an * (p - x) + dz + u + v;
        float zm = z - y;
        float t  = fabsf(zm) - 0.1f;
        float pr = (t > 0.f) ? copysignf(t, zm) : 0.f;
        float xn = x + (pr - z) + dz;
        XO[cc] = f2bf(xn); PO[cc] = f2bf(pr); YO[cc] = f2bf(y); ZO[cc] = f2bf(z);
        float e1 = pr - y; r += e1 * e1;
        float e2 = xn - z; d += e2 * e2;
    }
    *(s16x4*)(Sb + sb)            = xo;
    *(s16x4*)(Sb + sb + SVEC)     = po;
    *(s16x4*)(Sb + sb + 2 * SVEC) = yo;
    *(s16x4*)(Sb + sb + 3 * SVEC) = zo;
    #pragma unroll
    for (int cc = 0; cc < 2; ++cc) {
        s16x8 w; ushort* W = (ushort*)&w;
        #pragma unroll
        for (int t = 0; t < 2; ++t) {
            int jj = cc * 2 + t;
            W[t*4+0] = XO[jj]; W[t*4+1] = PO[jj];
            W[t*4+2] = YO[jj]; W[t*4+3] = ZO[jj];
        }
        int ch = (2 * fjg + cc) ^ (frow & 7);
        *(s16x8*)&buf[frow * 256 + ch * 8] = w;
    }
}

// step-19 variant: p_out f32 direct, r only, no Sb/A writes.
__device__ __forceinline__ void fin_last(float* __restrict__ dst,
                                         float an, float al,
                                         FbsReg& f, float& r) {
    float prf[4];
    const ushort* X = (const ushort*)&f.x4; const ushort* P = (const ushort*)&f.p4;
    const ushort* Y = (const ushort*)&f.y4; const ushort* Z = (const ushort*)&f.z4;
    const ushort* U = (const ushort*)&f.u4; const ushort* V = (const ushort*)&f.v4;
    #pragma unroll
    for (int cc = 0; cc < 4; ++cc) {
        float x = bf2f(X[cc]), p = bf2f(P[cc]);
        float yv = bf2f(Y[cc]), zv = bf2f(Z[cc]);
        float u = al * bf2f(U[cc]), v = al * bf2f(V[cc]);
        float y  = x + an * (yv - x) + u;
        float dz = an * (zv - p);
        float z  = x + an * (p - x) + dz + u + v;
        float zm = z - y;
        float t  = fabsf(zm) - 0.1f;
        float pr = (t > 0.f) ? copysignf(t, zm) : 0.f;
        prf[cc] = pr;
        float e1 = pr - y; r += e1 * e1;
    }
    *(float4*)dst = make_float4(prf[0], prf[1], prf[2], prf[3]);
}

// ---------- fused per-step kernel --------------------------------------------
// 1 block = 64 samples, 1024 threads (16 waves -> 4 waves/SIMD when VGPR<=128).
// grid = 256 = 1 block/CU. Each wave owns ONE 16-col N-frag in GEMM1/2
// (acc[4], rot[4] = 32 VGPR) and 5 frag-passes in GEMM3 -- per-wave state
// halved vs the 512-thr kernel so the 16-wave block fits 128 VGPR unspilled.
// Weight L2 stream unchanged (each Wf element read once per block).
template<bool LAST>
__global__ __launch_bounds__(1024) void k_step(
    ushort* __restrict__ Sb, ushort* __restrict__ uv,
    const ushort* __restrict__ Wf1, const ushort* __restrict__ Wf2,
    const ushort* __restrict__ Wf3,
    const float* __restrict__ b1v, const float* __restrict__ b2v,
    const float* __restrict__ b3v,
    const float* __restrict__ redprev, float* __restrict__ redcur,
    float an, float* __restrict__ pout) {
    __shared__ ushort As[2][64 * 256];        // 2 x 32 KB: A dbuf, then h1/h2
    const int tid  = threadIdx.x;
    const int wave = tid >> 6, lane = tid & 63;
    const int lm = lane & 15, quad = lane >> 4;
    const int sample0 = blockIdx.x * 64;
    const int frow = tid >> 4, fjg = tid & 15;  // FBS: 64 rows x 16 jgroups(x4)

    const s16x8* Wf1v = (const s16x8*)Wf1;
    const s16x8* Wf2v = (const s16x8*)Wf2;
    const s16x8* Wf3v = (const s16x8*)Wf3;

    // ---- inline alpha (same reduction as verified kernels) ----
    float av = (lane < 32) ? redprev[512 + lane * 16]
                           : redprev[1024 + (lane - 32) * 16];
    #pragma unroll
    for (int off = 16; off > 0; off >>= 1) av += __shfl_down(av, off);
    const float dsum = __shfl(av, 0), qsum = __shfl(av, 32);
    const float al = sqrtf(fminf(0.99f * fmaxf(dsum, 0.f) /
                                 (1.5f * qsum + 1e-12f), 1.f));

    const size_t srow = (size_t)(sample0 + frow) * INF  + fjg * 4;
    const size_t urow = (size_t)(sample0 + frow) * OUTF + fjg * 4;

    float r = 0.f, d = 0.f;

    if constexpr (LAST) {
        // ---- step 19: FBS-only, p_out f32 direct, r only, no barriers ----
        float* prow = pout + (size_t)(sample0 + frow) * SVEC + fjg * 4;
        FbsReg g0, g1;
        fbs_load(Sb, uv, srow,      urow,      g0);
        fbs_load(Sb, uv, srow + 64, urow + 64, g1);
        fin_last(prow,       an, al, g0, r);
        fbs_load(Sb, uv, srow + 128, urow + 128, g0);
        fin_last(prow + 64,  an, al, g1, r);
        fbs_load(Sb, uv, srow + 192, urow + 192, g1);
        fin_last(prow + 128, an, al, g0, r);
        fbs_load(Sb, uv, srow + 256, urow + 256, g0);
        fin_last(prow + 192, an, al, g1, r);
        fbs_load(Sb, uv, srow + 320, urow + 320, g1);
        fin_last(prow + 256, an, al, g0, r);
        fbs_load(Sb, uv, srow + 384, urow + 384, g0);
        fin_last(prow + 320, an, al, g1, r);
        fbs_load(Sb, uv, srow + 448, urow + 448, g1);
        fin_last(prow + 384, an, al, g0, r);
        fbs_load(Sb, uv, srow + 512, urow + 512, g0);
        fin_last(prow + 448, an, al, g1, r);
        fin_last(prow + 512, an, al, g0, r);
        #pragma unroll
        for (int off = 32; off > 0; off >>= 1) r += __shfl_down(r, off);
        if (lane == 0)
            atomicAdd(&redcur[(((blockIdx.x << 4) | wave) & 31) * 16], r);
        return;
    }

    FbsReg f;
    s16x8 b1[4];

    // prologue: chunk 0 + preload B steps 0,1,2 (f = wave)
    fbs_load(Sb, uv, srow, urow, f);
    fbs_finish(Sb, srow, As[0], frow, fjg, an, al, f, r, d);
    #pragma unroll
    for (int t = 0; t < 3; ++t)
        b1[t] = Wf1v[((size_t)wave * 72 + t) * 64 + lane];
    bar_lgkm();

    f32x4 acc[4];
    #pragma unroll
    for (int i = 0; i < 4; ++i) acc[i] = (f32x4){0.f, 0.f, 0.f, 0.f};

    for (int c = 0; c < 9; ++c) {
        const bool pf = (c < 8);
        const size_t sbn = srow + (size_t)(c + 1) * 64;
        const size_t ubn = urow + (size_t)(c + 1) * 64;
        if (pf) fbs_load(Sb, uv, sbn, ubn, f);   // issue early, use late
        const ushort* Ab = As[c & 1];
        #pragma unroll
        for (int kk = 0; kk < 8; ++kk) {
            // distance-3 prefetch; c*8 % 4 == 0 so slot = (kk+3)&3 is static
            if (c < 8 || kk < 5) {
                b1[(kk + 3) & 3] =
                    Wf1v[((size_t)wave * 72 + c * 8 + kk + 3) * 64 + lane];
            }
            s16x8 af[4];
            #pragma unroll
            for (int i = 0; i < 4; ++i)
                af[i] = *(const s16x8*)&Ab[(i * 16 + lm) * 256 +
                         ((((kk << 2) + quad) ^ (lm & 7)) << 3)];
            #pragma unroll
            for (int i = 0; i < 4; ++i)
                acc[i] = __builtin_amdgcn_mfma_f32_16x16x32_bf16(
                    af[i], b1[kk & 3], acc[i], 0, 0, 0);
        }
        if (pf) fbs_finish(Sb, sbn, As[(c + 1) & 1], frow, fjg, an, al, f, r, d);
        if (c < 8) bar_lgkm();   // no barrier after chunk 8 (As[1] reads were
                                 // fenced at the chunk-7 barrier)
    }

    // ---- r/d reductions ----
    #pragma unroll
    for (int off = 32; off > 0; off >>= 1) {
        r += __shfl_down(r, off);
        d += __shfl_down(d, off);
    }
    if (lane == 0) {
        int bk = ((blockIdx.x << 4) | wave) & 31;
        atomicAdd(&redcur[bk * 16],       r);
        atomicAdd(&redcur[512 + bk * 16], d);
    }

    // ---- h1 = relu(acc + b1) staged in LDS ----
    ushort* h1l = As[1];
    const float bb1 = b1v[wave * 16 + lm];
    #pragma unroll
    for (int i = 0; i < 4; ++i)
        #pragma unroll
        for (int rr = 0; rr < 4; ++rr) {
            int row = i * 16 + quad * 4 + rr;
            int col = wave * 16 + lm;
            float cv = fmaxf(acc[i][rr] + bb1, 0.f);
            h1l[row * 256 + ((((col >> 3) ^ (row & 7)) << 3) | (col & 7))] =
                f2bf(cv);
        }
    // preload GEMM2 kk=0,1,2 B-frags (global, no LDS dependency)
    s16x8 b2[4];
    #pragma unroll
    for (int t = 0; t < 3; ++t)
        b2[t] = Wf2v[((size_t)wave * 8 + t) * 64 + lane];
    bar_lgkm();

    // ---- GEMM2: h2 = relu(h1 @ W2 + b2), K = 256 ----
    f32x4 a2[4];
    #pragma unroll
    for (int i = 0; i < 4; ++i) a2[i] = (f32x4){0.f, 0.f, 0.f, 0.f};
    #pragma unroll
    for (int kk = 0; kk < 8; ++kk) {
        if (kk < 5)
            b2[(kk + 3) & 3] = Wf2v[((size_t)wave * 8 + kk + 3) * 64 + lane];
        s16x8 af[4];
        #pragma unroll
        for (int i = 0; i < 4; ++i)
            af[i] = *(const s16x8*)&h1l[(i * 16 + lm) * 256 +
                     ((((kk << 2) + quad) ^ (lm & 7)) << 3)];
        #pragma unroll
        for (int i = 0; i < 4; ++i)
            a2[i] = __builtin_amdgcn_mfma_f32_16x16x32_bf16(
                af[i], b2[kk & 3], a2[i], 0, 0, 0);
    }
    ushort* h2l = As[0];
    const float bb2 = b2v[wave * 16 + lm];
    #pragma unroll
    for (int i = 0; i < 4; ++i)
        #pragma unroll
        for (int rr = 0; rr < 4; ++rr) {
            int row = i * 16 + quad * 4 + rr;
            int col = wave * 16 + lm;
            float cv = fmaxf(a2[i][rr] + bb2, 0.f);
            h2l[row * 256 + ((((col >> 3) ^ (row & 7)) << 3) | (col & 7))] =
                f2bf(cv);
        }
    // preload GEMM3 t=0,1,2 B-frags (pass 0: f = wave)
    s16x8 b3[4];
    #pragma unroll
    for (int t = 0; t < 3; ++t)
        b3[t] = Wf3v[((size_t)wave * 8 + t) * 64 + lane];
    bar_lgkm();

    // ---- GEMM3: out = h2 @ W3 + b3 (no relu) ----
    // wave handles frags f = wave + 16*p, p = 0..4 (p==4 only for wave < 8).
    float q = 0.f;
    f32x4 a3[4];
    #pragma unroll
    for (int t = 0; t < 40; ++t) {
        const int p = t >> 3, kk = t & 7;
        const bool act = (p < 4) || (wave < 8);
        if (act) {
            const int t3 = t + 3, tp = t3 >> 3, tk = t3 & 7;
            if (t3 < 40 && (tp < 4 || wave < 8))
                b3[t3 & 3] = Wf3v[(((size_t)(wave + 16 * tp)) * 8 + tk) * 64 + lane];
            if (kk == 0) {
                #pragma unroll
                for (int i = 0; i < 4; ++i) a3[i] = (f32x4){0.f,0.f,0.f,0.f};
            }
            s16x8 af[4];
            #pragma unroll
            for (int i = 0; i < 4; ++i)
                af[i] = *(const s16x8*)&h2l[(i * 16 + lm) * 256 +
                         ((((kk << 2) + quad) ^ (lm & 7)) << 3)];
            #pragma unroll
            for (int i = 0; i < 4; ++i)
                a3[i] = __builtin_amdgcn_mfma_f32_16x16x32_bf16(
                    af[i], b3[t & 3], a3[i], 0, 0, 0);
            if (kk == 7) {                        // epilogue for frag f
                const int col = (wave + 16 * p) * 16 + lm;
                const float bb = b3v[col];
                #pragma unroll
                for (int i = 0; i < 4; ++i)
                    #pragma unroll
                    for (int rr = 0; rr < 4; ++rr) {
                        int row = i * 16 + quad * 4 + rr;
                        float cv = a3[i][rr] + bb;
                        q += cv * cv;
                        uv[(size_t)(sample0 + row) * OUTF + col] = f2bf(cv);
                    }
            }
        }
    }
    #pragma unroll
    for (int off = 32; off > 0; off >>= 1) q += __shfl_down(q, off);
    if (lane == 0)
        atomicAdd(&redcur[1024 + (((blockIdx.x << 4) | wave) & 31) * 16], q);
}

// ---------- residuals only (p_out written by k_step<true>) -------------------
__global__ __launch_bounds__(64) void k_res(const float* __restrict__ red,
                                            float* __restrict__ res_out) {
    int t = threadIdx.x;
    if (t >= TS) return;
    const float* rb = red + (size_t)(t + 1) * RSL;
    float s = 0.f;
    #pragma unroll
    for (int c = 0; c < 32; ++c) s += rb[c * 16];
    res_out[t] = sqrtf(s + 1e-12f);
}

extern "C" void kernel_launch(void* const* d_in, const int* in_sizes, int n_in,
                              void* d_out, int out_size, void* d_ws, size_t ws_size,
                              hipStream_t stream) {
    const float* noisy = (const float*)d_in[0];
    const float* W1 = (const float*)d_in[1];
    const float* b1 = (const float*)d_in[2];
    const float* W2 = (const float*)d_in[3];
    const float* b2 = (const float*)d_in[4];
    const float* W3 = (const float*)d_in[5];
    const float* b3 = (const float*)d_in[6];
    const int B = in_sizes[0] / 64;   // 16384

    // workspace layout (~115 MB)
    ushort* Sb  = (ushort*)d_ws;                        // [B,2304] bf16
    ushort* uv  = Sb + (size_t)B * INF;                 // [B,1152] bf16
    ushort* Wf1 = uv + (size_t)B * OUTF;                // 16*72*512 frag-linear
    ushort* Wf2 = Wf1 + (size_t)HID * INF;              // 16*8*512
    ushort* Wf3 = Wf2 + (size_t)HID * HID;              // 72*8*512
    float*  red = (float*)((((uintptr_t)(Wf3 + (size_t)OUTF * HID)) + 63) &
                           ~(uintptr_t)63);

    float* p_out   = (float*)d_out;                     // [B,576]
    float* res_out = p_out + (size_t)B * SVEC;          // [20]

    const int tot8S = B * 288;   // s16x8 slots in Sb

    k_init<<<(tot8S + 255) / 256, 256, 0, stream>>>(Sb, (const float4*)noisy, tot8S);
    k_zero<<<(21 * RSL + 127) / 128, 128, 0, stream>>>(red, 21 * RSL);
    // uv is NOT zeroed: step 0 has alpha == 0 (slot 0 zeroed), u=v=0*uv (finite).
    k_wf<<<(HID * INF + 255) / 256, 256, 0, stream>>>(W1, Wf1, 72, HID, 1, HID * INF);
    k_wf<<<(HID * HID + 255) / 256, 256, 0, stream>>>(W2, Wf2, 8, HID, 0, HID * HID);
    k_wf<<<(OUTF * HID + 255) / 256, 256, 0, stream>>>(W3, Wf3, 8, OUTF, 0, OUTF * HID);

    for (int n = 0; n < TS - 1; ++n) {
        float an = (float)n / ((float)n + 3.0f);
        k_step<false><<<B / 64, 1024, 0, stream>>>(
            Sb, uv, Wf1, Wf2, Wf3, b1, b2, b3,
            red + (size_t)n * RSL, red + (size_t)(n + 1) * RSL, an, p_out);
    }
    {
        float an = (float)(TS - 1) / ((float)(TS - 1) + 3.0f);
        k_step<true><<<B / 64, 1024, 0, stream>>>(
            Sb, uv, Wf1, Wf2, Wf3, b1, b2, b3,
            red + (size_t)(TS - 1) * RSL, red + (size_t)TS * RSL, an, p_out);
    }
    k_res<<<1, 64, 0, stream>>>(red, res_out);
}

// Round 9
// 1465.781 us; speedup vs baseline: 4.3843x; 1.0037x over previous
//
#include <hip/hip_runtime.h>
#include <math.h>

constexpr int SVEC = 576;    // N_CH * 64
constexpr int INF  = 2304;   // 4 * SVEC
constexpr int HID  = 256;
constexpr int OUTF = 1152;   // 2 * SVEC
constexpr int TS   = 20;
// red slot layout (line-spread buckets, 1 bucket = 1 cache line):
//   r[b] at b*16, d[b] at 512+b*16, q[b] at 1024+b*16, b in 0..31
constexpr int RSL  = 1536;   // floats per step slot (6 KB)

// ---------- helpers ----------------------------------------------------------
__device__ __forceinline__ ushort f2bf(float f) {    // RNE f32->bf16
    union { float f; unsigned u; } a; a.f = f;
    unsigned r = a.u + 0x7fff + ((a.u >> 16) & 1);
    return (ushort)(r >> 16);
}
__device__ __forceinline__ float bf2f(ushort b) {
    union { unsigned u; float f; } a; a.u = ((unsigned)b) << 16;
    return a.f;
}

// LDS-only barrier: orders ds ops across the block WITHOUT draining vmcnt.
// Cross-thread data in this kernel flows only through LDS; global rows are
// thread-private within a step.
__device__ __forceinline__ void bar_lgkm() {
    asm volatile("s_waitcnt lgkmcnt(0)\n\ts_barrier" ::: "memory");
}

typedef short  s16x8 __attribute__((ext_vector_type(8)));
typedef short  s16x4 __attribute__((ext_vector_type(4)));
typedef float  f32x4 __attribute__((ext_vector_type(4)));

// ---------- init: Sb(bf16) = [x|p|y|z] all = [noisy, 0...] -------------------
__global__ __launch_bounds__(256) void k_init(ushort* __restrict__ Sb,
                                              const float4* __restrict__ noisy4,
                                              int tot8) {
    int i = blockIdx.x * 256 + threadIdx.x;
    if (i >= tot8) return;
    int sample = i / 288;
    int j = i - sample * 288;
    int jc = j % 72;
    s16x8 o = (s16x8){0,0,0,0,0,0,0,0};
    if (jc < 8) {
        float4 a = noisy4[sample * 16 + jc * 2];
        float4 b = noisy4[sample * 16 + jc * 2 + 1];
        ushort* u = (ushort*)&o;
        u[0]=f2bf(a.x); u[1]=f2bf(a.y); u[2]=f2bf(a.z); u[3]=f2bf(a.w);
        u[4]=f2bf(b.x); u[5]=f2bf(b.y); u[6]=f2bf(b.z); u[7]=f2bf(b.w);
    }
    *(s16x8*)&Sb[(size_t)i * 8] = o;
}

__global__ __launch_bounds__(128) void k_zero(float* __restrict__ p, int n) {
    int i = blockIdx.x * 128 + threadIdx.x;
    if (i < n) p[i] = 0.f;
}

// ---------- fragment-linear weight repack (unchanged, verified) --------------
__global__ __launch_bounds__(256) void k_wf(const float* __restrict__ W,
                                            ushort* __restrict__ Wf,
                                            int KS, int stride, int perm,
                                            int total) {
    int o = blockIdx.x * 256 + threadIdx.x;
    if (o >= total) return;
    int e = o & 7;
    int lane = (o >> 3) & 63;
    int rem = o >> 9;
    int s = rem % KS, f = rem / KS;
    int quad = lane >> 4, lm = lane & 15;
    int kp = s * 32 + quad * 8 + e;
    int korig = perm ? (kp & 3) * 576 + (kp >> 2) : kp;
    int n = f * 16 + lm;
    Wf[o] = f2bf(W[(size_t)korig * stride + n]);
}

// ---------- FBS pieces (4 elems/thread; 1024-thread blocks, 64 rows) ---------
struct FbsReg { s16x4 x4, p4, y4, z4, u4, v4; };

__device__ __forceinline__ void fbs_load(const ushort* __restrict__ Sb,
                                         const ushort* __restrict__ uv,
                                         size_t sb, size_t ub, FbsReg& f) {
    f.x4 = *(const s16x4*)(Sb + sb);
    f.p4 = *(const s16x4*)(Sb + sb + SVEC);
    f.y4 = *(const s16x4*)(Sb + sb + 2 * SVEC);
    f.z4 = *(const s16x4*)(Sb + sb + 3 * SVEC);
    f.u4 = *(const s16x4*)(uv + ub);
    f.v4 = *(const s16x4*)(uv + ub + SVEC);
}

// FBS math identical to the verified kernels (R3's 4-elem variant, passed).
__device__ __forceinline__ void fbs_finish(ushort* __restrict__ Sb, size_t sb,
                                           ushort* __restrict__ buf,
                                           int frow, int fjg,
                                           float an, float al,
                                           FbsReg& f, float& r, float& d) {
    s16x4 xo, po, yo, zo;
    const ushort* X = (const ushort*)&f.x4; const ushort* P = (const ushort*)&f.p4;
    const ushort* Y = (const ushort*)&f.y4; const ushort* Z = (const ushort*)&f.z4;
    const ushort* U = (const ushort*)&f.u4; const ushort* V = (const ushort*)&f.v4;
    ushort* XO = (ushort*)&xo; ushort* PO = (ushort*)&po;
    ushort* YO = (ushort*)&yo; ushort* ZO = (ushort*)&zo;
    #pragma unroll
    for (int cc = 0; cc < 4; ++cc) {
        float x = bf2f(X[cc]), p = bf2f(P[cc]);
        float yv = bf2f(Y[cc]), zv = bf2f(Z[cc]);
        float u = al * bf2f(U[cc]), v = al * bf2f(V[cc]);
        float y  = x + an * (yv - x) + u;
        float dz = an * (zv - p);
        float z  = x + an * (p - x) + dz + u + v;
        float zm = z - y;
        float t  = fabsf(zm) - 0.1f;
        float pr = (t > 0.f) ? copysignf(t, zm) : 0.f;
        float xn = x + (pr - z) + dz;
        XO[cc] = f2bf(xn); PO[cc] = f2bf(pr); YO[cc] = f2bf(y); ZO[cc] = f2bf(z);
        float e1 = pr - y; r += e1 * e1;
        float e2 = xn - z; d += e2 * e2;
    }
    *(s16x4*)(Sb + sb)            = xo;
    *(s16x4*)(Sb + sb + SVEC)     = po;
    *(s16x4*)(Sb + sb + 2 * SVEC) = yo;
    *(s16x4*)(Sb + sb + 3 * SVEC) = zo;
    #pragma unroll
    for (int cc = 0; cc < 2; ++cc) {
        s16x8 w; ushort* W = (ushort*)&w;
        #pragma unroll
        for (int t = 0; t < 2; ++t) {
            int jj = cc * 2 + t;
            W[t*4+0] = XO[jj]; W[t*4+1] = PO[jj];
            W[t*4+2] = YO[jj]; W[t*4+3] = ZO[jj];
        }
        int ch = (2 * fjg + cc) ^ (frow & 7);
        *(s16x8*)&buf[frow * 256 + ch * 8] = w;
    }
}

// step-19 variant: p_out f32 direct, r only, no Sb/A writes.
__device__ __forceinline__ void fin_last(float* __restrict__ dst,
                                         float an, float al,
                                         FbsReg& f, float& r) {
    float prf[4];
    const ushort* X = (const ushort*)&f.x4; const ushort* P = (const ushort*)&f.p4;
    const ushort* Y = (const ushort*)&f.y4; const ushort* Z = (const ushort*)&f.z4;
    const ushort* U = (const ushort*)&f.u4; const ushort* V = (const ushort*)&f.v4;
    #pragma unroll
    for (int cc = 0; cc < 4; ++cc) {
        float x = bf2f(X[cc]), p = bf2f(P[cc]);
        float yv = bf2f(Y[cc]), zv = bf2f(Z[cc]);
        float u = al * bf2f(U[cc]), v = al * bf2f(V[cc]);
        float y  = x + an * (yv - x) + u;
        float dz = an * (zv - p);
        float z  = x + an * (p - x) + dz + u + v;
        float zm = z - y;
        float t  = fabsf(zm) - 0.1f;
        float pr = (t > 0.f) ? copysignf(t, zm) : 0.f;
        prf[cc] = pr;
        float e1 = pr - y; r += e1 * e1;
    }
    *(float4*)dst = make_float4(prf[0], prf[1], prf[2], prf[3]);
}

// ---------- fused per-step kernel --------------------------------------------
// 1 block = 64 samples, 1024 threads, grid = 256 = 1 block/CU = 16 waves/CU.
// __launch_bounds__(1024, 4): 4 waves/EU -> VGPR budget 128 (R8 defaulted to
// a 64-VGPR target for 2-block residency and spilled ~47 MB/dispatch).
// Each wave owns ONE 16-col N-frag in GEMM1/2 and 5 frag-passes in GEMM3.
template<bool LAST>
__global__ __launch_bounds__(1024, 4) void k_step(
    ushort* __restrict__ Sb, ushort* __restrict__ uv,
    const ushort* __restrict__ Wf1, const ushort* __restrict__ Wf2,
    const ushort* __restrict__ Wf3,
    const float* __restrict__ b1v, const float* __restrict__ b2v,
    const float* __restrict__ b3v,
    const float* __restrict__ redprev, float* __restrict__ redcur,
    float an, float* __restrict__ pout) {
    __shared__ ushort As[2][64 * 256];        // 2 x 32 KB: A dbuf, then h1/h2
    const int tid  = threadIdx.x;
    const int wave = tid >> 6, lane = tid & 63;
    const int lm = lane & 15, quad = lane >> 4;
    const int sample0 = blockIdx.x * 64;
    const int frow = tid >> 4, fjg = tid & 15;  // FBS: 64 rows x 16 jgroups(x4)

    const s16x8* Wf1v = (const s16x8*)Wf1;
    const s16x8* Wf2v = (const s16x8*)Wf2;
    const s16x8* Wf3v = (const s16x8*)Wf3;

    // ---- inline alpha (same reduction as verified kernels) ----
    float av = (lane < 32) ? redprev[512 + lane * 16]
                           : redprev[1024 + (lane - 32) * 16];
    #pragma unroll
    for (int off = 16; off > 0; off >>= 1) av += __shfl_down(av, off);
    const float dsum = __shfl(av, 0), qsum = __shfl(av, 32);
    const float al = sqrtf(fminf(0.99f * fmaxf(dsum, 0.f) /
                                 (1.5f * qsum + 1e-12f), 1.f));

    const size_t srow = (size_t)(sample0 + frow) * INF  + fjg * 4;
    const size_t urow = (size_t)(sample0 + frow) * OUTF + fjg * 4;

    float r = 0.f, d = 0.f;

    if constexpr (LAST) {
        // ---- step 19: FBS-only, p_out f32 direct, r only, no barriers ----
        float* prow = pout + (size_t)(sample0 + frow) * SVEC + fjg * 4;
        FbsReg g0, g1;
        fbs_load(Sb, uv, srow,      urow,      g0);
        fbs_load(Sb, uv, srow + 64, urow + 64, g1);
        fin_last(prow,       an, al, g0, r);
        fbs_load(Sb, uv, srow + 128, urow + 128, g0);
        fin_last(prow + 64,  an, al, g1, r);
        fbs_load(Sb, uv, srow + 192, urow + 192, g1);
        fin_last(prow + 128, an, al, g0, r);
        fbs_load(Sb, uv, srow + 256, urow + 256, g0);
        fin_last(prow + 192, an, al, g1, r);
        fbs_load(Sb, uv, srow + 320, urow + 320, g1);
        fin_last(prow + 256, an, al, g0, r);
        fbs_load(Sb, uv, srow + 384, urow + 384, g0);
        fin_last(prow + 320, an, al, g1, r);
        fbs_load(Sb, uv, srow + 448, urow + 448, g1);
        fin_last(prow + 384, an, al, g0, r);
        fbs_load(Sb, uv, srow + 512, urow + 512, g0);
        fin_last(prow + 448, an, al, g1, r);
        fin_last(prow + 512, an, al, g0, r);
        #pragma unroll
        for (int off = 32; off > 0; off >>= 1) r += __shfl_down(r, off);
        if (lane == 0)
            atomicAdd(&redcur[(((blockIdx.x << 4) | wave) & 31) * 16], r);
        return;
    }

    FbsReg f;
    s16x8 b1[4];

    // prologue: chunk 0 + preload B steps 0,1,2 (f = wave)
    fbs_load(Sb, uv, srow, urow, f);
    fbs_finish(Sb, srow, As[0], frow, fjg, an, al, f, r, d);
    #pragma unroll
    for (int t = 0; t < 3; ++t)
        b1[t] = Wf1v[((size_t)wave * 72 + t) * 64 + lane];
    bar_lgkm();

    f32x4 acc[4];
    #pragma unroll
    for (int i = 0; i < 4; ++i) acc[i] = (f32x4){0.f, 0.f, 0.f, 0.f};

    for (int c = 0; c < 9; ++c) {
        const bool pf = (c < 8);
        const size_t sbn = srow + (size_t)(c + 1) * 64;
        const size_t ubn = urow + (size_t)(c + 1) * 64;
        if (pf) fbs_load(Sb, uv, sbn, ubn, f);   // issue early, use late
        const ushort* Ab = As[c & 1];
        #pragma unroll
        for (int kk = 0; kk < 8; ++kk) {
            // distance-3 prefetch; c*8 % 4 == 0 so slot = (kk+3)&3 is static
            if (c < 8 || kk < 5) {
                b1[(kk + 3) & 3] =
                    Wf1v[((size_t)wave * 72 + c * 8 + kk + 3) * 64 + lane];
            }
            s16x8 af[4];
            #pragma unroll
            for (int i = 0; i < 4; ++i)
                af[i] = *(const s16x8*)&Ab[(i * 16 + lm) * 256 +
                         ((((kk << 2) + quad) ^ (lm & 7)) << 3)];
            #pragma unroll
            for (int i = 0; i < 4; ++i)
                acc[i] = __builtin_amdgcn_mfma_f32_16x16x32_bf16(
                    af[i], b1[kk & 3], acc[i], 0, 0, 0);
        }
        if (pf) fbs_finish(Sb, sbn, As[(c + 1) & 1], frow, fjg, an, al, f, r, d);
        if (c < 8) bar_lgkm();   // no barrier after chunk 8 (As[1] reads were
                                 // fenced at the chunk-7 barrier)
    }

    // ---- r/d reductions ----
    #pragma unroll
    for (int off = 32; off > 0; off >>= 1) {
        r += __shfl_down(r, off);
        d += __shfl_down(d, off);
    }
    if (lane == 0) {
        int bk = ((blockIdx.x << 4) | wave) & 31;
        atomicAdd(&redcur[bk * 16],       r);
        atomicAdd(&redcur[512 + bk * 16], d);
    }

    // ---- h1 = relu(acc + b1) staged in LDS ----
    ushort* h1l = As[1];
    const float bb1 = b1v[wave * 16 + lm];
    #pragma unroll
    for (int i = 0; i < 4; ++i)
        #pragma unroll
        for (int rr = 0; rr < 4; ++rr) {
            int row = i * 16 + quad * 4 + rr;
            int col = wave * 16 + lm;
            float cv = fmaxf(acc[i][rr] + bb1, 0.f);
            h1l[row * 256 + ((((col >> 3) ^ (row & 7)) << 3) | (col & 7))] =
                f2bf(cv);
        }
    // preload GEMM2 kk=0,1,2 B-frags (global, no LDS dependency)
    s16x8 b2[4];
    #pragma unroll
    for (int t = 0; t < 3; ++t)
        b2[t] = Wf2v[((size_t)wave * 8 + t) * 64 + lane];
    bar_lgkm();

    // ---- GEMM2: h2 = relu(h1 @ W2 + b2), K = 256 ----
    f32x4 a2[4];
    #pragma unroll
    for (int i = 0; i < 4; ++i) a2[i] = (f32x4){0.f, 0.f, 0.f, 0.f};
    #pragma unroll
    for (int kk = 0; kk < 8; ++kk) {
        if (kk < 5)
            b2[(kk + 3) & 3] = Wf2v[((size_t)wave * 8 + kk + 3) * 64 + lane];
        s16x8 af[4];
        #pragma unroll
        for (int i = 0; i < 4; ++i)
            af[i] = *(const s16x8*)&h1l[(i * 16 + lm) * 256 +
                     ((((kk << 2) + quad) ^ (lm & 7)) << 3)];
        #pragma unroll
        for (int i = 0; i < 4; ++i)
            a2[i] = __builtin_amdgcn_mfma_f32_16x16x32_bf16(
                af[i], b2[kk & 3], a2[i], 0, 0, 0);
    }
    ushort* h2l = As[0];
    const float bb2 = b2v[wave * 16 + lm];
    #pragma unroll
    for (int i = 0; i < 4; ++i)
        #pragma unroll
        for (int rr = 0; rr < 4; ++rr) {
            int row = i * 16 + quad * 4 + rr;
            int col = wave * 16 + lm;
            float cv = fmaxf(a2[i][rr] + bb2, 0.f);
            h2l[row * 256 + ((((col >> 3) ^ (row & 7)) << 3) | (col & 7))] =
                f2bf(cv);
        }
    // preload GEMM3 t=0,1,2 B-frags (pass 0: f = wave)
    s16x8 b3[4];
    #pragma unroll
    for (int t = 0; t < 3; ++t)
        b3[t] = Wf3v[((size_t)wave * 8 + t) * 64 + lane];
    bar_lgkm();

    // ---- GEMM3: out = h2 @ W3 + b3 (no relu) ----
    // wave handles frags f = wave + 16*p, p = 0..4 (p==4 only for wave < 8).
    float q = 0.f;
    f32x4 a3[4];
    #pragma unroll
    for (int t = 0; t < 40; ++t) {
        const int p = t >> 3, kk = t & 7;
        const bool act = (p < 4) || (wave < 8);
        if (act) {
            const int t3 = t + 3, tp = t3 >> 3, tk = t3 & 7;
            if (t3 < 40 && (tp < 4 || wave < 8))
                b3[t3 & 3] = Wf3v[(((size_t)(wave + 16 * tp)) * 8 + tk) * 64 + lane];
            if (kk == 0) {
                #pragma unroll
                for (int i = 0; i < 4; ++i) a3[i] = (f32x4){0.f,0.f,0.f,0.f};
            }
            s16x8 af[4];
            #pragma unroll
            for (int i = 0; i < 4; ++i)
                af[i] = *(const s16x8*)&h2l[(i * 16 + lm) * 256 +
                         ((((kk << 2) + quad) ^ (lm & 7)) << 3)];
            #pragma unroll
            for (int i = 0; i < 4; ++i)
                a3[i] = __builtin_amdgcn_mfma_f32_16x16x32_bf16(
                    af[i], b3[t & 3], a3[i], 0, 0, 0);
            if (kk == 7) {                        // epilogue for frag f
                const int col = (wave + 16 * p) * 16 + lm;
                const float bb = b3v[col];
                #pragma unroll
                for (int i = 0; i < 4; ++i)
                    #pragma unroll
                    for (int rr = 0; rr < 4; ++rr) {
                        int row = i * 16 + quad * 4 + rr;
                        float cv = a3[i][rr] + bb;
                        q += cv * cv;
                        uv[(size_t)(sample0 + row) * OUTF + col] = f2bf(cv);
                    }
            }
        }
    }
    #pragma unroll
    for (int off = 32; off > 0; off >>= 1) q += __shfl_down(q, off);
    if (lane == 0)
        atomicAdd(&redcur[1024 + (((blockIdx.x << 4) | wave) & 31) * 16], q);
}

// ---------- residuals only (p_out written by k_step<true>) -------------------
__global__ __launch_bounds__(64) void k_res(const float* __restrict__ red,
                                            float* __restrict__ res_out) {
    int t = threadIdx.x;
    if (t >= TS) return;
    const float* rb = red + (size_t)(t + 1) * RSL;
    float s = 0.f;
    #pragma unroll
    for (int c = 0; c < 32; ++c) s += rb[c * 16];
    res_out[t] = sqrtf(s + 1e-12f);
}

extern "C" void kernel_launch(void* const* d_in, const int* in_sizes, int n_in,
                              void* d_out, int out_size, void* d_ws, size_t ws_size,
                              hipStream_t stream) {
    const float* noisy = (const float*)d_in[0];
    const float* W1 = (const float*)d_in[1];
    const float* b1 = (const float*)d_in[2];
    const float* W2 = (const float*)d_in[3];
    const float* b2 = (const float*)d_in[4];
    const float* W3 = (const float*)d_in[5];
    const float* b3 = (const float*)d_in[6];
    const int B = in_sizes[0] / 64;   // 16384

    // workspace layout (~115 MB)
    ushort* Sb  = (ushort*)d_ws;                        // [B,2304] bf16
    ushort* uv  = Sb + (size_t)B * INF;                 // [B,1152] bf16
    ushort* Wf1 = uv + (size_t)B * OUTF;                // 16*72*512 frag-linear
    ushort* Wf2 = Wf1 + (size_t)HID * INF;              // 16*8*512
    ushort* Wf3 = Wf2 + (size_t)HID * HID;              // 72*8*512
    float*  red = (float*)((((uintptr_t)(Wf3 + (size_t)OUTF * HID)) + 63) &
                           ~(uintptr_t)63);

    float* p_out   = (float*)d_out;                     // [B,576]
    float* res_out = p_out + (size_t)B * SVEC;          // [20]

    const int tot8S = B * 288;   // s16x8 slots in Sb

    k_init<<<(tot8S + 255) / 256, 256, 0, stream>>>(Sb, (const float4*)noisy, tot8S);
    k_zero<<<(21 * RSL + 127) / 128, 128, 0, stream>>>(red, 21 * RSL);
    // uv is NOT zeroed: step 0 has alpha == 0 (slot 0 zeroed), u=v=0*uv (finite).
    k_wf<<<(HID * INF + 255) / 256, 256, 0, stream>>>(W1, Wf1, 72, HID, 1, HID * INF);
    k_wf<<<(HID * HID + 255) / 256, 256, 0, stream>>>(W2, Wf2, 8, HID, 0, HID * HID);
    k_wf<<<(OUTF * HID + 255) / 256, 256, 0, stream>>>(W3, Wf3, 8, OUTF, 0, OUTF * HID);

    for (int n = 0; n < TS - 1; ++n) {
        float an = (float)n / ((float)n + 3.0f);
        k_step<false><<<B / 64, 1024, 0, stream>>>(
            Sb, uv, Wf1, Wf2, Wf3, b1, b2, b3,
            red + (size_t)n * RSL, red + (size_t)(n + 1) * RSL, an, p_out);
    }
    {
        float an = (float)(TS - 1) / ((float)(TS - 1) + 3.0f);
        k_step<true><<<B / 64, 1024, 0, stream>>>(
            Sb, uv, Wf1, Wf2, Wf3, b1, b2, b3,
            red + (size_t)(TS - 1) * RSL, red + (size_t)TS * RSL, an, p_out);
    }
    k_res<<<1, 64, 0, stream>>>(red, res_out);
}

// Round 10
// 1460.789 us; speedup vs baseline: 4.3993x; 1.0034x over previous
//
#include <hip/hip_runtime.h>
#include <math.h>

constexpr int SVEC = 576;    // N_CH * 64
constexpr int INF  = 2304;   // 4 * SVEC
constexpr int HID  = 256;
constexpr int OUTF = 1152;   // 2 * SVEC
constexpr int TS   = 20;
// red slot layout (line-spread buckets, 1 bucket = 1 cache line):
//   r[b] at b*16, d[b] at 512+b*16, q[b] at 1024+b*16, b in 0..31
constexpr int RSL  = 1536;   // floats per step slot (6 KB)

// ---------- helpers ----------------------------------------------------------
__device__ __forceinline__ ushort f2bf(float f) {    // RNE f32->bf16
    union { float f; unsigned u; } a; a.f = f;
    unsigned r = a.u + 0x7fff + ((a.u >> 16) & 1);
    return (ushort)(r >> 16);
}
__device__ __forceinline__ float bf2f(ushort b) {
    union { unsigned u; float f; } a; a.u = ((unsigned)b) << 16;
    return a.f;
}

// LDS-only barrier: orders ds ops across the block WITHOUT draining vmcnt.
// Cross-thread data in this kernel flows only through LDS; global rows are
// thread-private within a step.
__device__ __forceinline__ void bar_lgkm() {
    asm volatile("s_waitcnt lgkmcnt(0)\n\ts_barrier" ::: "memory");
}

typedef short  s16x8 __attribute__((ext_vector_type(8)));
typedef short  s16x4 __attribute__((ext_vector_type(4)));
typedef float  f32x4 __attribute__((ext_vector_type(4)));

// ---------- init: Sb(bf16) = [x|p|y|z] all = [noisy, 0...] -------------------
__global__ __launch_bounds__(256) void k_init(ushort* __restrict__ Sb,
                                              const float4* __restrict__ noisy4,
                                              int tot8) {
    int i = blockIdx.x * 256 + threadIdx.x;
    if (i >= tot8) return;
    int sample = i / 288;
    int j = i - sample * 288;
    int jc = j % 72;
    s16x8 o = (s16x8){0,0,0,0,0,0,0,0};
    if (jc < 8) {
        float4 a = noisy4[sample * 16 + jc * 2];
        float4 b = noisy4[sample * 16 + jc * 2 + 1];
        ushort* u = (ushort*)&o;
        u[0]=f2bf(a.x); u[1]=f2bf(a.y); u[2]=f2bf(a.z); u[3]=f2bf(a.w);
        u[4]=f2bf(b.x); u[5]=f2bf(b.y); u[6]=f2bf(b.z); u[7]=f2bf(b.w);
    }
    *(s16x8*)&Sb[(size_t)i * 8] = o;
}

__global__ __launch_bounds__(128) void k_zero(float* __restrict__ p, int n) {
    int i = blockIdx.x * 128 + threadIdx.x;
    if (i < n) p[i] = 0.f;
}

// ---------- fragment-linear weight repack (unchanged, verified) --------------
__global__ __launch_bounds__(256) void k_wf(const float* __restrict__ W,
                                            ushort* __restrict__ Wf,
                                            int KS, int stride, int perm,
                                            int total) {
    int o = blockIdx.x * 256 + threadIdx.x;
    if (o >= total) return;
    int e = o & 7;
    int lane = (o >> 3) & 63;
    int rem = o >> 9;
    int s = rem % KS, f = rem / KS;
    int quad = lane >> 4, lm = lane & 15;
    int kp = s * 32 + quad * 8 + e;
    int korig = perm ? (kp & 3) * 576 + (kp >> 2) : kp;
    int n = f * 16 + lm;
    Wf[o] = f2bf(W[(size_t)korig * stride + n]);
}

// ---------- FBS pieces (4 elems/thread; 1024-thread blocks, 64 rows) ---------
struct FbsReg { s16x4 x4, p4, y4, z4, u4, v4; };

__device__ __forceinline__ void fbs_load(const ushort* __restrict__ Sb,
                                         const ushort* __restrict__ uv,
                                         size_t sb, size_t ub, FbsReg& f) {
    f.x4 = *(const s16x4*)(Sb + sb);
    f.p4 = *(const s16x4*)(Sb + sb + SVEC);
    f.y4 = *(const s16x4*)(Sb + sb + 2 * SVEC);
    f.z4 = *(const s16x4*)(Sb + sb + 3 * SVEC);
    f.u4 = *(const s16x4*)(uv + ub);
    f.v4 = *(const s16x4*)(uv + ub + SVEC);
}

// FBS math identical to the verified kernels (R3's 4-elem variant, passed).
__device__ __forceinline__ void fbs_finish(ushort* __restrict__ Sb, size_t sb,
                                           ushort* __restrict__ buf,
                                           int frow, int fjg,
                                           float an, float al,
                                           FbsReg& f, float& r, float& d) {
    s16x4 xo, po, yo, zo;
    const ushort* X = (const ushort*)&f.x4; const ushort* P = (const ushort*)&f.p4;
    const ushort* Y = (const ushort*)&f.y4; const ushort* Z = (const ushort*)&f.z4;
    const ushort* U = (const ushort*)&f.u4; const ushort* V = (const ushort*)&f.v4;
    ushort* XO = (ushort*)&xo; ushort* PO = (ushort*)&po;
    ushort* YO = (ushort*)&yo; ushort* ZO = (ushort*)&zo;
    #pragma unroll
    for (int cc = 0; cc < 4; ++cc) {
        float x = bf2f(X[cc]), p = bf2f(P[cc]);
        float yv = bf2f(Y[cc]), zv = bf2f(Z[cc]);
        float u = al * bf2f(U[cc]), v = al * bf2f(V[cc]);
        float y  = x + an * (yv - x) + u;
        float dz = an * (zv - p);
        float z  = x + an * (p - x) + dz + u + v;
        float zm = z - y;
        float t  = fabsf(zm) - 0.1f;
        float pr = (t > 0.f) ? copysignf(t, zm) : 0.f;
        float xn = x + (pr - z) + dz;
        XO[cc] = f2bf(xn); PO[cc] = f2bf(pr); YO[cc] = f2bf(y); ZO[cc] = f2bf(z);
        float e1 = pr - y; r += e1 * e1;
        float e2 = xn - z; d += e2 * e2;
    }
    *(s16x4*)(Sb + sb)            = xo;
    *(s16x4*)(Sb + sb + SVEC)     = po;
    *(s16x4*)(Sb + sb + 2 * SVEC) = yo;
    *(s16x4*)(Sb + sb + 3 * SVEC) = zo;
    #pragma unroll
    for (int cc = 0; cc < 2; ++cc) {
        s16x8 w; ushort* W = (ushort*)&w;
        #pragma unroll
        for (int t = 0; t < 2; ++t) {
            int jj = cc * 2 + t;
            W[t*4+0] = XO[jj]; W[t*4+1] = PO[jj];
            W[t*4+2] = YO[jj]; W[t*4+3] = ZO[jj];
        }
        int ch = (2 * fjg + cc) ^ (frow & 7);
        *(s16x8*)&buf[frow * 256 + ch * 8] = w;
    }
}

// step-19 variant: p_out f32 direct, r only, no Sb/A writes.
__device__ __forceinline__ void fin_last(float* __restrict__ dst,
                                         float an, float al,
                                         FbsReg& f, float& r) {
    float prf[4];
    const ushort* X = (const ushort*)&f.x4; const ushort* P = (const ushort*)&f.p4;
    const ushort* Y = (const ushort*)&f.y4; const ushort* Z = (const ushort*)&f.z4;
    const ushort* U = (const ushort*)&f.u4; const ushort* V = (const ushort*)&f.v4;
    #pragma unroll
    for (int cc = 0; cc < 4; ++cc) {
        float x = bf2f(X[cc]), p = bf2f(P[cc]);
        float yv = bf2f(Y[cc]), zv = bf2f(Z[cc]);
        float u = al * bf2f(U[cc]), v = al * bf2f(V[cc]);
        float y  = x + an * (yv - x) + u;
        float dz = an * (zv - p);
        float z  = x + an * (p - x) + dz + u + v;
        float zm = z - y;
        float t  = fabsf(zm) - 0.1f;
        float pr = (t > 0.f) ? copysignf(t, zm) : 0.f;
        prf[cc] = pr;
        float e1 = pr - y; r += e1 * e1;
    }
    *(float4*)dst = make_float4(prf[0], prf[1], prf[2], prf[3]);
}

// ---------- fused per-step kernel --------------------------------------------
// 1 block = 64 samples, 1024 threads, grid = 256 = 1 block/CU = 16 waves/CU.
// __launch_bounds__(1024, 1): the 2nd arg behaves as min BLOCKS/CU (measured
// R3/R5/R8/R9: arg=4 -> 64-VGPR target + spill; arg=2 @512thr -> 128).
// 1 block/CU * 16 waves = 4 waves/SIMD -> VGPR budget 128, fits ~100 unspilled.
// Each wave owns ONE 16-col N-frag in GEMM1/2 and 5 frag-passes in GEMM3.
template<bool LAST>
__global__ __launch_bounds__(1024, 1) void k_step(
    ushort* __restrict__ Sb, ushort* __restrict__ uv,
    const ushort* __restrict__ Wf1, const ushort* __restrict__ Wf2,
    const ushort* __restrict__ Wf3,
    const float* __restrict__ b1v, const float* __restrict__ b2v,
    const float* __restrict__ b3v,
    const float* __restrict__ redprev, float* __restrict__ redcur,
    float an, float* __restrict__ pout) {
    __shared__ ushort As[2][64 * 256];        // 2 x 32 KB: A dbuf, then h1/h2
    const int tid  = threadIdx.x;
    const int wave = tid >> 6, lane = tid & 63;
    const int lm = lane & 15, quad = lane >> 4;
    const int sample0 = blockIdx.x * 64;
    const int frow = tid >> 4, fjg = tid & 15;  // FBS: 64 rows x 16 jgroups(x4)

    const s16x8* Wf1v = (const s16x8*)Wf1;
    const s16x8* Wf2v = (const s16x8*)Wf2;
    const s16x8* Wf3v = (const s16x8*)Wf3;

    // ---- inline alpha (same reduction as verified kernels) ----
    float av = (lane < 32) ? redprev[512 + lane * 16]
                           : redprev[1024 + (lane - 32) * 16];
    #pragma unroll
    for (int off = 16; off > 0; off >>= 1) av += __shfl_down(av, off);
    const float dsum = __shfl(av, 0), qsum = __shfl(av, 32);
    const float al = sqrtf(fminf(0.99f * fmaxf(dsum, 0.f) /
                                 (1.5f * qsum + 1e-12f), 1.f));

    const size_t srow = (size_t)(sample0 + frow) * INF  + fjg * 4;
    const size_t urow = (size_t)(sample0 + frow) * OUTF + fjg * 4;

    float r = 0.f, d = 0.f;

    if constexpr (LAST) {
        // ---- step 19: FBS-only, p_out f32 direct, r only, no barriers ----
        float* prow = pout + (size_t)(sample0 + frow) * SVEC + fjg * 4;
        FbsReg g0, g1;
        fbs_load(Sb, uv, srow,      urow,      g0);
        fbs_load(Sb, uv, srow + 64, urow + 64, g1);
        fin_last(prow,       an, al, g0, r);
        fbs_load(Sb, uv, srow + 128, urow + 128, g0);
        fin_last(prow + 64,  an, al, g1, r);
        fbs_load(Sb, uv, srow + 192, urow + 192, g1);
        fin_last(prow + 128, an, al, g0, r);
        fbs_load(Sb, uv, srow + 256, urow + 256, g0);
        fin_last(prow + 192, an, al, g1, r);
        fbs_load(Sb, uv, srow + 320, urow + 320, g1);
        fin_last(prow + 256, an, al, g0, r);
        fbs_load(Sb, uv, srow + 384, urow + 384, g0);
        fin_last(prow + 320, an, al, g1, r);
        fbs_load(Sb, uv, srow + 448, urow + 448, g1);
        fin_last(prow + 384, an, al, g0, r);
        fbs_load(Sb, uv, srow + 512, urow + 512, g0);
        fin_last(prow + 448, an, al, g1, r);
        fin_last(prow + 512, an, al, g0, r);
        #pragma unroll
        for (int off = 32; off > 0; off >>= 1) r += __shfl_down(r, off);
        if (lane == 0)
            atomicAdd(&redcur[(((blockIdx.x << 4) | wave) & 31) * 16], r);
        return;
    }

    FbsReg f;
    s16x8 b1[4];

    // prologue: chunk 0 + preload B steps 0,1,2 (f = wave)
    fbs_load(Sb, uv, srow, urow, f);
    fbs_finish(Sb, srow, As[0], frow, fjg, an, al, f, r, d);
    #pragma unroll
    for (int t = 0; t < 3; ++t)
        b1[t] = Wf1v[((size_t)wave * 72 + t) * 64 + lane];
    bar_lgkm();

    f32x4 acc[4];
    #pragma unroll
    for (int i = 0; i < 4; ++i) acc[i] = (f32x4){0.f, 0.f, 0.f, 0.f};

    for (int c = 0; c < 9; ++c) {
        const bool pf = (c < 8);
        const size_t sbn = srow + (size_t)(c + 1) * 64;
        const size_t ubn = urow + (size_t)(c + 1) * 64;
        if (pf) fbs_load(Sb, uv, sbn, ubn, f);   // issue early, use late
        const ushort* Ab = As[c & 1];
        #pragma unroll
        for (int kk = 0; kk < 8; ++kk) {
            // distance-3 prefetch; c*8 % 4 == 0 so slot = (kk+3)&3 is static
            if (c < 8 || kk < 5) {
                b1[(kk + 3) & 3] =
                    Wf1v[((size_t)wave * 72 + c * 8 + kk + 3) * 64 + lane];
            }
            s16x8 af[4];
            #pragma unroll
            for (int i = 0; i < 4; ++i)
                af[i] = *(const s16x8*)&Ab[(i * 16 + lm) * 256 +
                         ((((kk << 2) + quad) ^ (lm & 7)) << 3)];
            #pragma unroll
            for (int i = 0; i < 4; ++i)
                acc[i] = __builtin_amdgcn_mfma_f32_16x16x32_bf16(
                    af[i], b1[kk & 3], acc[i], 0, 0, 0);
        }
        if (pf) fbs_finish(Sb, sbn, As[(c + 1) & 1], frow, fjg, an, al, f, r, d);
        if (c < 8) bar_lgkm();   // no barrier after chunk 8 (As[1] reads were
                                 // fenced at the chunk-7 barrier)
    }

    // ---- r/d reductions ----
    #pragma unroll
    for (int off = 32; off > 0; off >>= 1) {
        r += __shfl_down(r, off);
        d += __shfl_down(d, off);
    }
    if (lane == 0) {
        int bk = ((blockIdx.x << 4) | wave) & 31;
        atomicAdd(&redcur[bk * 16],       r);
        atomicAdd(&redcur[512 + bk * 16], d);
    }

    // ---- h1 = relu(acc + b1) staged in LDS ----
    ushort* h1l = As[1];
    const float bb1 = b1v[wave * 16 + lm];
    #pragma unroll
    for (int i = 0; i < 4; ++i)
        #pragma unroll
        for (int rr = 0; rr < 4; ++rr) {
            int row = i * 16 + quad * 4 + rr;
            int col = wave * 16 + lm;
            float cv = fmaxf(acc[i][rr] + bb1, 0.f);
            h1l[row * 256 + ((((col >> 3) ^ (row & 7)) << 3) | (col & 7))] =
                f2bf(cv);
        }
    // preload GEMM2 kk=0,1,2 B-frags (global, no LDS dependency)
    s16x8 b2[4];
    #pragma unroll
    for (int t = 0; t < 3; ++t)
        b2[t] = Wf2v[((size_t)wave * 8 + t) * 64 + lane];
    bar_lgkm();

    // ---- GEMM2: h2 = relu(h1 @ W2 + b2), K = 256 ----
    f32x4 a2[4];
    #pragma unroll
    for (int i = 0; i < 4; ++i) a2[i] = (f32x4){0.f, 0.f, 0.f, 0.f};
    #pragma unroll
    for (int kk = 0; kk < 8; ++kk) {
        if (kk < 5)
            b2[(kk + 3) & 3] = Wf2v[((size_t)wave * 8 + kk + 3) * 64 + lane];
        s16x8 af[4];
        #pragma unroll
        for (int i = 0; i < 4; ++i)
            af[i] = *(const s16x8*)&h1l[(i * 16 + lm) * 256 +
                     ((((kk << 2) + quad) ^ (lm & 7)) << 3)];
        #pragma unroll
        for (int i = 0; i < 4; ++i)
            a2[i] = __builtin_amdgcn_mfma_f32_16x16x32_bf16(
                af[i], b2[kk & 3], a2[i], 0, 0, 0);
    }
    ushort* h2l = As[0];
    const float bb2 = b2v[wave * 16 + lm];
    #pragma unroll
    for (int i = 0; i < 4; ++i)
        #pragma unroll
        for (int rr = 0; rr < 4; ++rr) {
            int row = i * 16 + quad * 4 + rr;
            int col = wave * 16 + lm;
            float cv = fmaxf(a2[i][rr] + bb2, 0.f);
            h2l[row * 256 + ((((col >> 3) ^ (row & 7)) << 3) | (col & 7))] =
                f2bf(cv);
        }
    // preload GEMM3 t=0,1,2 B-frags (pass 0: f = wave)
    s16x8 b3[4];
    #pragma unroll
    for (int t = 0; t < 3; ++t)
        b3[t] = Wf3v[((size_t)wave * 8 + t) * 64 + lane];
    bar_lgkm();

    // ---- GEMM3: out = h2 @ W3 + b3 (no relu) ----
    // wave handles frags f = wave + 16*p, p = 0..4 (p==4 only for wave < 8).
    float q = 0.f;
    f32x4 a3[4];
    #pragma unroll
    for (int t = 0; t < 40; ++t) {
        const int p = t >> 3, kk = t & 7;
        const bool act = (p < 4) || (wave < 8);
        if (act) {
            const int t3 = t + 3, tp = t3 >> 3, tk = t3 & 7;
            if (t3 < 40 && (tp < 4 || wave < 8))
                b3[t3 & 3] = Wf3v[(((size_t)(wave + 16 * tp)) * 8 + tk) * 64 + lane];
            if (kk == 0) {
                #pragma unroll
                for (int i = 0; i < 4; ++i) a3[i] = (f32x4){0.f,0.f,0.f,0.f};
            }
            s16x8 af[4];
            #pragma unroll
            for (int i = 0; i < 4; ++i)
                af[i] = *(const s16x8*)&h2l[(i * 16 + lm) * 256 +
                         ((((kk << 2) + quad) ^ (lm & 7)) << 3)];
            #pragma unroll
            for (int i = 0; i < 4; ++i)
                a3[i] = __builtin_amdgcn_mfma_f32_16x16x32_bf16(
                    af[i], b3[t & 3], a3[i], 0, 0, 0);
            if (kk == 7) {                        // epilogue for frag f
                const int col = (wave + 16 * p) * 16 + lm;
                const float bb = b3v[col];
                #pragma unroll
                for (int i = 0; i < 4; ++i)
                    #pragma unroll
                    for (int rr = 0; rr < 4; ++rr) {
                        int row = i * 16 + quad * 4 + rr;
                        float cv = a3[i][rr] + bb;
                        q += cv * cv;
                        uv[(size_t)(sample0 + row) * OUTF + col] = f2bf(cv);
                    }
            }
        }
    }
    #pragma unroll
    for (int off = 32; off > 0; off >>= 1) q += __shfl_down(q, off);
    if (lane == 0)
        atomicAdd(&redcur[1024 + (((blockIdx.x << 4) | wave) & 31) * 16], q);
}

// ---------- residuals only (p_out written by k_step<true>) -------------------
__global__ __launch_bounds__(64) void k_res(const float* __restrict__ red,
                                            float* __restrict__ res_out) {
    int t = threadIdx.x;
    if (t >= TS) return;
    const float* rb = red + (size_t)(t + 1) * RSL;
    float s = 0.f;
    #pragma unroll
    for (int c = 0; c < 32; ++c) s += rb[c * 16];
    res_out[t] = sqrtf(s + 1e-12f);
}

extern "C" void kernel_launch(void* const* d_in, const int* in_sizes, int n_in,
                              void* d_out, int out_size, void* d_ws, size_t ws_size,
                              hipStream_t stream) {
    const float* noisy = (const float*)d_in[0];
    const float* W1 = (const float*)d_in[1];
    const float* b1 = (const float*)d_in[2];
    const float* W2 = (const float*)d_in[3];
    const float* b2 = (const float*)d_in[4];
    const float* W3 = (const float*)d_in[5];
    const float* b3 = (const float*)d_in[6];
    const int B = in_sizes[0] / 64;   // 16384

    // workspace layout (~115 MB)
    ushort* Sb  = (ushort*)d_ws;                        // [B,2304] bf16
    ushort* uv  = Sb + (size_t)B * INF;                 // [B,1152] bf16
    ushort* Wf1 = uv + (size_t)B * OUTF;                // 16*72*512 frag-linear
    ushort* Wf2 = Wf1 + (size_t)HID * INF;              // 16*8*512
    ushort* Wf3 = Wf2 + (size_t)HID * HID;              // 72*8*512
    float*  red = (float*)((((uintptr_t)(Wf3 + (size_t)OUTF * HID)) + 63) &
                           ~(uintptr_t)63);

    float* p_out   = (float*)d_out;                     // [B,576]
    float* res_out = p_out + (size_t)B * SVEC;          // [20]

    const int tot8S = B * 288;   // s16x8 slots in Sb

    k_init<<<(tot8S + 255) / 256, 256, 0, stream>>>(Sb, (const float4*)noisy, tot8S);
    k_zero<<<(21 * RSL + 127) / 128, 128, 0, stream>>>(red, 21 * RSL);
    // uv is NOT zeroed: step 0 has alpha == 0 (slot 0 zeroed), u=v=0*uv (finite).
    k_wf<<<(HID * INF + 255) / 256, 256, 0, stream>>>(W1, Wf1, 72, HID, 1, HID * INF);
    k_wf<<<(HID * HID + 255) / 256, 256, 0, stream>>>(W2, Wf2, 8, HID, 0, HID * HID);
    k_wf<<<(OUTF * HID + 255) / 256, 256, 0, stream>>>(W3, Wf3, 8, OUTF, 0, OUTF * HID);

    for (int n = 0; n < TS - 1; ++n) {
        float an = (float)n / ((float)n + 3.0f);
        k_step<false><<<B / 64, 1024, 0, stream>>>(
            Sb, uv, Wf1, Wf2, Wf3, b1, b2, b3,
            red + (size_t)n * RSL, red + (size_t)(n + 1) * RSL, an, p_out);
    }
    {
        float an = (float)(TS - 1) / ((float)(TS - 1) + 3.0f);
        k_step<true><<<B / 64, 1024, 0, stream>>>(
            Sb, uv, Wf1, Wf2, Wf3, b1, b2, b3,
            red + (size_t)(TS - 1) * RSL, red + (size_t)TS * RSL, an, p_out);
    }
    k_res<<<1, 64, 0, stream>>>(red, res_out);
}

// Round 11
// 1390.740 us; speedup vs baseline: 4.6209x; 1.0504x over previous
//
#include <hip/hip_runtime.h>
#include <math.h>

constexpr int SVEC = 576;    // N_CH * 64
constexpr int INF  = 2304;   // 4 * SVEC
constexpr int HID  = 256;
constexpr int OUTF = 1152;   // 2 * SVEC
constexpr int TS   = 20;
// red slot layout (line-spread buckets, 1 bucket = 1 cache line):
//   r[b] at b*16, d[b] at 512+b*16, q[b] at 1024+b*16, b in 0..31
constexpr int RSL  = 1536;   // floats per step slot (6 KB)

// ---------- helpers ----------------------------------------------------------
__device__ __forceinline__ ushort f2bf(float f) {    // RNE f32->bf16
    union { float f; unsigned u; } a; a.f = f;
    unsigned r = a.u + 0x7fff + ((a.u >> 16) & 1);
    return (ushort)(r >> 16);
}
__device__ __forceinline__ float bf2f(ushort b) {
    union { unsigned u; float f; } a; a.u = ((unsigned)b) << 16;
    return a.f;
}

// LDS-only barrier: orders ds ops across the block WITHOUT draining vmcnt.
// Cross-thread data in this kernel flows only through LDS; global rows are
// thread-private within a step.
__device__ __forceinline__ void bar_lgkm() {
    asm volatile("s_waitcnt lgkmcnt(0)\n\ts_barrier" ::: "memory");
}

typedef short  s16x8 __attribute__((ext_vector_type(8)));
typedef float  f32x4 __attribute__((ext_vector_type(4)));

// ---------- init: Sb(bf16) = [x|p|y|z] all = [noisy, 0...] -------------------
__global__ __launch_bounds__(256) void k_init(ushort* __restrict__ Sb,
                                              const float4* __restrict__ noisy4,
                                              int tot8) {
    int i = blockIdx.x * 256 + threadIdx.x;
    if (i >= tot8) return;
    int sample = i / 288;
    int j = i - sample * 288;
    int jc = j % 72;
    s16x8 o = (s16x8){0,0,0,0,0,0,0,0};
    if (jc < 8) {
        float4 a = noisy4[sample * 16 + jc * 2];
        float4 b = noisy4[sample * 16 + jc * 2 + 1];
        ushort* u = (ushort*)&o;
        u[0]=f2bf(a.x); u[1]=f2bf(a.y); u[2]=f2bf(a.z); u[3]=f2bf(a.w);
        u[4]=f2bf(b.x); u[5]=f2bf(b.y); u[6]=f2bf(b.z); u[7]=f2bf(b.w);
    }
    *(s16x8*)&Sb[(size_t)i * 8] = o;
}

__global__ __launch_bounds__(128) void k_zero(float* __restrict__ p, int n) {
    int i = blockIdx.x * 128 + threadIdx.x;
    if (i < n) p[i] = 0.f;
}

// ---------- fragment-linear weight repack (unchanged, verified) --------------
__global__ __launch_bounds__(256) void k_wf(const float* __restrict__ W,
                                            ushort* __restrict__ Wf,
                                            int KS, int stride, int perm,
                                            int total) {
    int o = blockIdx.x * 256 + threadIdx.x;
    if (o >= total) return;
    int e = o & 7;
    int lane = (o >> 3) & 63;
    int rem = o >> 9;
    int s = rem % KS, f = rem / KS;
    int quad = lane >> 4, lm = lane & 15;
    int kp = s * 32 + quad * 8 + e;
    int korig = perm ? (kp & 3) * 576 + (kp >> 2) : kp;
    int n = f * 16 + lm;
    Wf[o] = f2bf(W[(size_t)korig * stride + n]);
}

// ---------- FBS pieces (8 elems/thread; 512-thread blocks, 64 rows) ----------
struct FbsReg { s16x8 x8, p8, y8, z8, u8, v8; };

// LOADUV=false (step 0): alpha==0 makes u=v=0 regardless of uv content, so
// skip the 37.7 MB poison read and splat zeros (bit-exact: 0*denorm==0*0==0).
template<bool LOADUV>
__device__ __forceinline__ void fbs_load(const ushort* __restrict__ Sb,
                                         const ushort* __restrict__ uv,
                                         size_t sb, size_t ub, FbsReg& f) {
    f.x8 = *(const s16x8*)(Sb + sb);
    f.p8 = *(const s16x8*)(Sb + sb + SVEC);
    f.y8 = *(const s16x8*)(Sb + sb + 2 * SVEC);
    f.z8 = *(const s16x8*)(Sb + sb + 3 * SVEC);
    if (LOADUV) {
        f.u8 = *(const s16x8*)(uv + ub);
        f.v8 = *(const s16x8*)(uv + ub + SVEC);
    } else {
        f.u8 = (s16x8){0,0,0,0,0,0,0,0};
        f.v8 = (s16x8){0,0,0,0,0,0,0,0};
    }
}

// math identical to the verified k_fbs; writes Sb in place and writes the
// interleaved k'=4j+b slab into the LDS A-buffer (XOR-swizzled 16B chunks:
// chunk ^ (row&7), same function applied on the MFMA read side).
__device__ __forceinline__ void fbs_finish(ushort* __restrict__ Sb, size_t sb,
                                           ushort* __restrict__ buf,
                                           int frow, int fjg,
                                           float an, float al,
                                           FbsReg& f, float& r, float& d) {
    s16x8 xo, po, yo, zo;
    const ushort* X = (const ushort*)&f.x8; const ushort* P = (const ushort*)&f.p8;
    const ushort* Y = (const ushort*)&f.y8; const ushort* Z = (const ushort*)&f.z8;
    const ushort* U = (const ushort*)&f.u8; const ushort* V = (const ushort*)&f.v8;
    ushort* XO = (ushort*)&xo; ushort* PO = (ushort*)&po;
    ushort* YO = (ushort*)&yo; ushort* ZO = (ushort*)&zo;
    #pragma unroll
    for (int cc = 0; cc < 8; ++cc) {
        float x = bf2f(X[cc]), p = bf2f(P[cc]);
        float yv = bf2f(Y[cc]), zv = bf2f(Z[cc]);
        float u = al * bf2f(U[cc]), v = al * bf2f(V[cc]);
        float y  = x + an * (yv - x) + u;
        float dz = an * (zv - p);
        float z  = x + an * (p - x) + dz + u + v;
        float zm = z - y;
        float t  = fabsf(zm) - 0.1f;
        float pr = (t > 0.f) ? copysignf(t, zm) : 0.f;
        float xn = x + (pr - z) + dz;
        XO[cc] = f2bf(xn); PO[cc] = f2bf(pr); YO[cc] = f2bf(y); ZO[cc] = f2bf(z);
        float e1 = pr - y; r += e1 * e1;
        float e2 = xn - z; d += e2 * e2;
    }
    *(s16x8*)(Sb + sb)            = xo;
    *(s16x8*)(Sb + sb + SVEC)     = po;
    *(s16x8*)(Sb + sb + 2 * SVEC) = yo;
    *(s16x8*)(Sb + sb + 3 * SVEC) = zo;
    #pragma unroll
    for (int cc = 0; cc < 4; ++cc) {
        s16x8 w; ushort* W = (ushort*)&w;
        #pragma unroll
        for (int t = 0; t < 2; ++t) {
            int jj = cc * 2 + t;
            W[t*4+0] = XO[jj]; W[t*4+1] = PO[jj];
            W[t*4+2] = YO[jj]; W[t*4+3] = ZO[jj];
        }
        int ch = (4 * fjg + cc) ^ (frow & 7);
        *(s16x8*)&buf[frow * 256 + ch * 8] = w;
    }
}

// step-19 variant: p_out f32 direct, r only, no Sb/A writes (x,p,y,z,uv dead
// after this step; only pr and the residual survive).
__device__ __forceinline__ void fin_last(float* __restrict__ dst,
                                         float an, float al,
                                         FbsReg& f, float& r) {
    float prf[8];
    const ushort* X = (const ushort*)&f.x8; const ushort* P = (const ushort*)&f.p8;
    const ushort* Y = (const ushort*)&f.y8; const ushort* Z = (const ushort*)&f.z8;
    const ushort* U = (const ushort*)&f.u8; const ushort* V = (const ushort*)&f.v8;
    #pragma unroll
    for (int cc = 0; cc < 8; ++cc) {
        float x = bf2f(X[cc]), p = bf2f(P[cc]);
        float yv = bf2f(Y[cc]), zv = bf2f(Z[cc]);
        float u = al * bf2f(U[cc]), v = al * bf2f(V[cc]);
        float y  = x + an * (yv - x) + u;
        float dz = an * (zv - p);
        float z  = x + an * (p - x) + dz + u + v;
        float zm = z - y;
        float t  = fabsf(zm) - 0.1f;
        float pr = (t > 0.f) ? copysignf(t, zm) : 0.f;
        prf[cc] = pr;
        float e1 = pr - y; r += e1 * e1;
    }
    *(float4*)(dst)     = make_float4(prf[0], prf[1], prf[2], prf[3]);
    *(float4*)(dst + 4) = make_float4(prf[4], prf[5], prf[6], prf[7]);
}

// ---------- fused per-step kernel (R5 structure, verified @1435us) -----------
// 1 block = 64 samples, 512 threads (8 waves). grid = 256 = 1 block/CU.
// MODE: 0 = first step (skip uv reads), 1 = middle, 2 = last (FBS-only,
// writes p_out f32 directly, no GEMMs / Sb writeback / barriers).
template<int MODE>
__global__ __launch_bounds__(512, 2) void k_step(
    ushort* __restrict__ Sb, ushort* __restrict__ uv,
    const ushort* __restrict__ Wf1, const ushort* __restrict__ Wf2,
    const ushort* __restrict__ Wf3,
    const float* __restrict__ b1v, const float* __restrict__ b2v,
    const float* __restrict__ b3v,
    const float* __restrict__ redprev, float* __restrict__ redcur,
    float an, float* __restrict__ pout) {
    __shared__ ushort As[2][64 * 256];        // 2 x 32 KB: A dbuf, then h1/h2
    const int tid  = threadIdx.x;
    const int wave = tid >> 6, lane = tid & 63;
    const int lm = lane & 15, quad = lane >> 4;
    const int sample0 = blockIdx.x * 64;
    const int frow = tid >> 3, fjg = tid & 7;   // FBS: 64 rows x 8 jgroups

    const s16x8* Wf1v = (const s16x8*)Wf1;
    const s16x8* Wf2v = (const s16x8*)Wf2;
    const s16x8* Wf3v = (const s16x8*)Wf3;

    // ---- inline alpha (same reduction as verified kernels) ----
    float av = (lane < 32) ? redprev[512 + lane * 16]
                           : redprev[1024 + (lane - 32) * 16];
    #pragma unroll
    for (int off = 16; off > 0; off >>= 1) av += __shfl_down(av, off);
    const float dsum = __shfl(av, 0), qsum = __shfl(av, 32);
    const float al = sqrtf(fminf(0.99f * fmaxf(dsum, 0.f) /
                                 (1.5f * qsum + 1e-12f), 1.f));

    const size_t srow = (size_t)(sample0 + frow) * INF  + fjg * 8;
    const size_t urow = (size_t)(sample0 + frow) * OUTF + fjg * 8;

    float r = 0.f, d = 0.f;

    if constexpr (MODE == 2) {
        // ---- step 19: FBS-only, p_out f32 direct, r only, no barriers ----
        float* prow = pout + (size_t)(sample0 + frow) * SVEC + fjg * 8;
        FbsReg g0, g1;
        fbs_load<true>(Sb, uv, srow,      urow,      g0);
        fbs_load<true>(Sb, uv, srow + 64, urow + 64, g1);
        fin_last(prow,       an, al, g0, r);
        fbs_load<true>(Sb, uv, srow + 128, urow + 128, g0);
        fin_last(prow + 64,  an, al, g1, r);
        fbs_load<true>(Sb, uv, srow + 192, urow + 192, g1);
        fin_last(prow + 128, an, al, g0, r);
        fbs_load<true>(Sb, uv, srow + 256, urow + 256, g0);
        fin_last(prow + 192, an, al, g1, r);
        fbs_load<true>(Sb, uv, srow + 320, urow + 320, g1);
        fin_last(prow + 256, an, al, g0, r);
        fbs_load<true>(Sb, uv, srow + 384, urow + 384, g0);
        fin_last(prow + 320, an, al, g1, r);
        fbs_load<true>(Sb, uv, srow + 448, urow + 448, g1);
        fin_last(prow + 384, an, al, g0, r);
        fbs_load<true>(Sb, uv, srow + 512, urow + 512, g0);
        fin_last(prow + 448, an, al, g1, r);
        fin_last(prow + 512, an, al, g0, r);
        #pragma unroll
        for (int off = 32; off > 0; off >>= 1) r += __shfl_down(r, off);
        if (lane == 0)
            atomicAdd(&redcur[(((blockIdx.x << 3) | wave) & 31) * 16], r);
        return;
    }

    constexpr bool LUV = (MODE != 0);
    FbsReg f;
    s16x8 b1[4][2];

    // prologue: chunk 0 + preload B steps 0,1,2
    fbs_load<LUV>(Sb, uv, srow, urow, f);
    fbs_finish(Sb, srow, As[0], frow, fjg, an, al, f, r, d);
    #pragma unroll
    for (int t = 0; t < 3; ++t)
        #pragma unroll
        for (int j = 0; j < 2; ++j)
            b1[t][j] = Wf1v[((wave * 2 + j) * 72 + t) * 64 + lane];
    bar_lgkm();

    f32x4 acc[4][2];
    #pragma unroll
    for (int i = 0; i < 4; ++i)
        #pragma unroll
        for (int j = 0; j < 2; ++j) acc[i][j] = (f32x4){0.f, 0.f, 0.f, 0.f};

    for (int c = 0; c < 9; ++c) {
        const bool pf = (c < 8);
        const size_t sbn = srow + (size_t)(c + 1) * 64;
        const size_t ubn = urow + (size_t)(c + 1) * 64;
        if (pf) fbs_load<LUV>(Sb, uv, sbn, ubn, f);  // issue early, use late
        const ushort* Ab = As[c & 1];
        #pragma unroll
        for (int kk = 0; kk < 8; ++kk) {
            // distance-3 prefetch; c*8 % 4 == 0 so slot = (kk+3)&3 is static
            if (c < 8 || kk < 5) {
                const int tg3 = c * 8 + kk + 3;
                #pragma unroll
                for (int j = 0; j < 2; ++j)
                    b1[(kk + 3) & 3][j] =
                        Wf1v[((wave * 2 + j) * 72 + tg3) * 64 + lane];
            }
            s16x8 af[4];
            #pragma unroll
            for (int i = 0; i < 4; ++i)
                af[i] = *(const s16x8*)&Ab[(i * 16 + lm) * 256 +
                         ((((kk << 2) + quad) ^ (lm & 7)) << 3)];
            #pragma unroll
            for (int i = 0; i < 4; ++i)
                #pragma unroll
                for (int j = 0; j < 2; ++j)
                    acc[i][j] = __builtin_amdgcn_mfma_f32_16x16x32_bf16(
                        af[i], b1[kk & 3][j], acc[i][j], 0, 0, 0);
        }
        if (pf) fbs_finish(Sb, sbn, As[(c + 1) & 1], frow, fjg, an, al, f, r, d);
        if (c < 8) bar_lgkm();   // no barrier after chunk 8 (As[1] reads were
                                 // fenced at the chunk-7 barrier)
    }

    // ---- r/d reductions ----
    #pragma unroll
    for (int off = 32; off > 0; off >>= 1) {
        r += __shfl_down(r, off);
        d += __shfl_down(d, off);
    }
    if (lane == 0) {
        int bk = ((blockIdx.x << 3) | wave) & 31;
        atomicAdd(&redcur[bk * 16],       r);
        atomicAdd(&redcur[512 + bk * 16], d);
    }

    // ---- h1 = relu(acc + b1) staged in LDS ----
    ushort* h1l = As[1];
    float bb1[2];
    #pragma unroll
    for (int j = 0; j < 2; ++j) bb1[j] = b1v[wave * 32 + j * 16 + lm];
    #pragma unroll
    for (int i = 0; i < 4; ++i)
        #pragma unroll
        for (int j = 0; j < 2; ++j)
            #pragma unroll
            for (int rr = 0; rr < 4; ++rr) {
                int row = i * 16 + quad * 4 + rr;
                int col = wave * 32 + j * 16 + lm;
                float cv = fmaxf(acc[i][j][rr] + bb1[j], 0.f);
                h1l[row * 256 + ((((col >> 3) ^ (row & 7)) << 3) | (col & 7))] =
                    f2bf(cv);
            }
    // preload GEMM2 kk=0,1,2 B-frags (global, no LDS dependency)
    s16x8 b2[4][2];
    #pragma unroll
    for (int t = 0; t < 3; ++t)
        #pragma unroll
        for (int j = 0; j < 2; ++j)
            b2[t][j] = Wf2v[((wave * 2 + j) * 8 + t) * 64 + lane];
    bar_lgkm();

    // ---- GEMM2: h2 = relu(h1 @ W2 + b2), K = 256 ----
    f32x4 a2[4][2];
    #pragma unroll
    for (int i = 0; i < 4; ++i)
        #pragma unroll
        for (int j = 0; j < 2; ++j) a2[i][j] = (f32x4){0.f, 0.f, 0.f, 0.f};
    #pragma unroll
    for (int kk = 0; kk < 8; ++kk) {
        if (kk < 5) {
            #pragma unroll
            for (int j = 0; j < 2; ++j)
                b2[(kk + 3) & 3][j] =
                    Wf2v[((wave * 2 + j) * 8 + kk + 3) * 64 + lane];
        }
        s16x8 af[4];
        #pragma unroll
        for (int i = 0; i < 4; ++i)
            af[i] = *(const s16x8*)&h1l[(i * 16 + lm) * 256 +
                     ((((kk << 2) + quad) ^ (lm & 7)) << 3)];
        #pragma unroll
        for (int i = 0; i < 4; ++i)
            #pragma unroll
            for (int j = 0; j < 2; ++j)
                a2[i][j] = __builtin_amdgcn_mfma_f32_16x16x32_bf16(
                    af[i], b2[kk & 3][j], a2[i][j], 0, 0, 0);
    }
    ushort* h2l = As[0];
    float bb2[2];
    #pragma unroll
    for (int j = 0; j < 2; ++j) bb2[j] = b2v[wave * 32 + j * 16 + lm];
    #pragma unroll
    for (int i = 0; i < 4; ++i)
        #pragma unroll
        for (int j = 0; j < 2; ++j)
            #pragma unroll
            for (int rr = 0; rr < 4; ++rr) {
                int row = i * 16 + quad * 4 + rr;
                int col = wave * 32 + j * 16 + lm;
                float cv = fmaxf(a2[i][j][rr] + bb2[j], 0.f);
                h2l[row * 256 + ((((col >> 3) ^ (row & 7)) << 3) | (col & 7))] =
                    f2bf(cv);
            }
    // preload GEMM3 t=0,1,2 B-frags
    s16x8 b3[4][3];
    #pragma unroll
    for (int t = 0; t < 3; ++t)
        #pragma unroll
        for (int jj = 0; jj < 3; ++jj)
            b3[t][jj] = Wf3v[((wave * 9 + jj) * 8 + t) * 64 + lane];
    bar_lgkm();

    // ---- GEMM3: out = h2 @ W3 + b3 (no relu), 144 cols/wave, 3 passes ----
    float q = 0.f;
    f32x4 a3[3][4];
    #pragma unroll
    for (int t = 0; t < 24; ++t) {
        const int p = t >> 3, kk = t & 7;
        if (t < 21) {                             // distance-3, crosses passes
            const int tp = (t + 3) >> 3, tk = (t + 3) & 7;
            #pragma unroll
            for (int jj = 0; jj < 3; ++jj)
                b3[(t + 3) & 3][jj] =
                    Wf3v[((wave * 9 + tp * 3 + jj) * 8 + tk) * 64 + lane];
        }
        if (kk == 0) {
            #pragma unroll
            for (int jj = 0; jj < 3; ++jj)
                #pragma unroll
                for (int i = 0; i < 4; ++i) a3[jj][i] = (f32x4){0.f,0.f,0.f,0.f};
        }
        s16x8 af[4];
        #pragma unroll
        for (int i = 0; i < 4; ++i)
            af[i] = *(const s16x8*)&h2l[(i * 16 + lm) * 256 +
                     ((((kk << 2) + quad) ^ (lm & 7)) << 3)];
        #pragma unroll
        for (int jj = 0; jj < 3; ++jj)
            #pragma unroll
            for (int i = 0; i < 4; ++i)
                a3[jj][i] = __builtin_amdgcn_mfma_f32_16x16x32_bf16(
                    af[i], b3[t & 3][jj], a3[jj][i], 0, 0, 0);
        if (kk == 7) {                            // epilogue for pass p
            #pragma unroll
            for (int jj = 0; jj < 3; ++jj) {
                int col = (wave * 9 + p * 3 + jj) * 16 + lm;
                float bb = b3v[col];
                #pragma unroll
                for (int i = 0; i < 4; ++i)
                    #pragma unroll
                    for (int rr = 0; rr < 4; ++rr) {
                        int row = i * 16 + quad * 4 + rr;
                        float cv = a3[jj][i][rr] + bb;
                        q += cv * cv;
                        uv[(size_t)(sample0 + row) * OUTF + col] = f2bf(cv);
                    }
            }
        }
    }
    #pragma unroll
    for (int off = 32; off > 0; off >>= 1) q += __shfl_down(q, off);
    if (lane == 0)
        atomicAdd(&redcur[1024 + (((blockIdx.x << 3) | wave) & 31) * 16], q);
}

// ---------- residuals only (p_out written by k_step<2>) ----------------------
__global__ __launch_bounds__(64) void k_res(const float* __restrict__ red,
                                            float* __restrict__ res_out) {
    int t = threadIdx.x;
    if (t >= TS) return;
    const float* rb = red + (size_t)(t + 1) * RSL;
    float s = 0.f;
    #pragma unroll
    for (int c = 0; c < 32; ++c) s += rb[c * 16];
    res_out[t] = sqrtf(s + 1e-12f);
}

extern "C" void kernel_launch(void* const* d_in, const int* in_sizes, int n_in,
                              void* d_out, int out_size, void* d_ws, size_t ws_size,
                              hipStream_t stream) {
    const float* noisy = (const float*)d_in[0];
    const float* W1 = (const float*)d_in[1];
    const float* b1 = (const float*)d_in[2];
    const float* W2 = (const float*)d_in[3];
    const float* b2 = (const float*)d_in[4];
    const float* W3 = (const float*)d_in[5];
    const float* b3 = (const float*)d_in[6];
    const int B = in_sizes[0] / 64;   // 16384

    // workspace layout (~115 MB)
    ushort* Sb  = (ushort*)d_ws;                        // [B,2304] bf16
    ushort* uv  = Sb + (size_t)B * INF;                 // [B,1152] bf16
    ushort* Wf1 = uv + (size_t)B * OUTF;                // 16*72*512 frag-linear
    ushort* Wf2 = Wf1 + (size_t)HID * INF;              // 16*8*512
    ushort* Wf3 = Wf2 + (size_t)HID * HID;              // 72*8*512
    float*  red = (float*)((((uintptr_t)(Wf3 + (size_t)OUTF * HID)) + 63) &
                           ~(uintptr_t)63);

    float* p_out   = (float*)d_out;                     // [B,576]
    float* res_out = p_out + (size_t)B * SVEC;          // [20]

    const int tot8S = B * 288;   // s16x8 slots in Sb

    k_init<<<(tot8S + 255) / 256, 256, 0, stream>>>(Sb, (const float4*)noisy, tot8S);
    k_zero<<<(21 * RSL + 127) / 128, 128, 0, stream>>>(red, 21 * RSL);
    // uv is NOT zeroed: step 0 uses MODE=0 (uv never read there).
    k_wf<<<(HID * INF + 255) / 256, 256, 0, stream>>>(W1, Wf1, 72, HID, 1, HID * INF);
    k_wf<<<(HID * HID + 255) / 256, 256, 0, stream>>>(W2, Wf2, 8, HID, 0, HID * HID);
    k_wf<<<(OUTF * HID + 255) / 256, 256, 0, stream>>>(W3, Wf3, 8, OUTF, 0, OUTF * HID);

    k_step<0><<<B / 64, 512, 0, stream>>>(
        Sb, uv, Wf1, Wf2, Wf3, b1, b2, b3,
        red, red + RSL, 0.0f, p_out);
    for (int n = 1; n < TS - 1; ++n) {
        float an = (float)n / ((float)n + 3.0f);
        k_step<1><<<B / 64, 512, 0, stream>>>(
            Sb, uv, Wf1, Wf2, Wf3, b1, b2, b3,
            red + (size_t)n * RSL, red + (size_t)(n + 1) * RSL, an, p_out);
    }
    {
        float an = (float)(TS - 1) / ((float)(TS - 1) + 3.0f);
        k_step<2><<<B / 64, 512, 0, stream>>>(
            Sb, uv, Wf1, Wf2, Wf3, b1, b2, b3,
            red + (size_t)(TS - 1) * RSL, red + (size_t)TS * RSL, an, p_out);
    }
    k_res<<<1, 64, 0, stream>>>(red, res_out);
}

// Round 12
// 1236.021 us; speedup vs baseline: 5.1993x; 1.1252x over previous
//
#include <hip/hip_runtime.h>
#include <math.h>

constexpr int SVEC = 576;    // N_CH * 64
constexpr int INF  = 2304;   // 4 * SVEC
constexpr int HID  = 256;
constexpr int OUTF = 1152;   // 2 * SVEC
constexpr int TS   = 20;
// red slot layout (line-spread buckets, 1 bucket = 1 cache line):
//   r[b] at b*16, d[b] at 512+b*16, q[b] at 1024+b*16, b in 0..31
constexpr int RSL  = 1536;   // floats per step slot (6 KB)

// ---------- helpers ----------------------------------------------------------
__device__ __forceinline__ ushort f2bf(float f) {    // RNE f32->bf16
    union { float f; unsigned u; } a; a.f = f;
    unsigned r = a.u + 0x7fff + ((a.u >> 16) & 1);
    return (ushort)(r >> 16);
}
__device__ __forceinline__ float bf2f(ushort b) {
    union { unsigned u; float f; } a; a.u = ((unsigned)b) << 16;
    return a.f;
}

// LDS-only barrier: orders ds ops across the block WITHOUT draining vmcnt.
// Cross-thread data in this kernel flows only through LDS; global rows are
// thread-private within a step.
__device__ __forceinline__ void bar_lgkm() {
    asm volatile("s_waitcnt lgkmcnt(0)\n\ts_barrier" ::: "memory");
}

typedef short  s16x8 __attribute__((ext_vector_type(8)));
typedef float  f32x4 __attribute__((ext_vector_type(4)));

// ---------- init: Sb(bf16) = [x|p|y|z] all = [noisy, 0...] -------------------
__global__ __launch_bounds__(256) void k_init(ushort* __restrict__ Sb,
                                              const float4* __restrict__ noisy4,
                                              int tot8) {
    int i = blockIdx.x * 256 + threadIdx.x;
    if (i >= tot8) return;
    int sample = i / 288;
    int j = i - sample * 288;
    int jc = j % 72;
    s16x8 o = (s16x8){0,0,0,0,0,0,0,0};
    if (jc < 8) {
        float4 a = noisy4[sample * 16 + jc * 2];
        float4 b = noisy4[sample * 16 + jc * 2 + 1];
        ushort* u = (ushort*)&o;
        u[0]=f2bf(a.x); u[1]=f2bf(a.y); u[2]=f2bf(a.z); u[3]=f2bf(a.w);
        u[4]=f2bf(b.x); u[5]=f2bf(b.y); u[6]=f2bf(b.z); u[7]=f2bf(b.w);
    }
    *(s16x8*)&Sb[(size_t)i * 8] = o;
}

__global__ __launch_bounds__(128) void k_zero(float* __restrict__ p, int n) {
    int i = blockIdx.x * 128 + threadIdx.x;
    if (i < n) p[i] = 0.f;
}

// ---------- fragment-linear weight repack (unchanged, verified) --------------
__global__ __launch_bounds__(256) void k_wf(const float* __restrict__ W,
                                            ushort* __restrict__ Wf,
                                            int KS, int stride, int perm,
                                            int total) {
    int o = blockIdx.x * 256 + threadIdx.x;
    if (o >= total) return;
    int e = o & 7;
    int lane = (o >> 3) & 63;
    int rem = o >> 9;
    int s = rem % KS, f = rem / KS;
    int quad = lane >> 4, lm = lane & 15;
    int kp = s * 32 + quad * 8 + e;
    int korig = perm ? (kp & 3) * 576 + (kp >> 2) : kp;
    int n = f * 16 + lm;
    Wf[o] = f2bf(W[(size_t)korig * stride + n]);
}

// ---------- FBS pieces (8 elems/thread; 512-thread blocks, 64 rows) ----------
struct FbsReg { s16x8 x8, p8, y8, z8, u8, v8; };

// LOADUV=false (step 0): alpha==0 makes u=v=0 regardless of uv content, so
// skip the 37.7 MB poison read and splat zeros (bit-exact: 0*denorm==0*0==0).
template<bool LOADUV>
__device__ __forceinline__ void fbs_load(const ushort* __restrict__ Sb,
                                         const ushort* __restrict__ uv,
                                         size_t sb, size_t ub, FbsReg& f) {
    f.x8 = *(const s16x8*)(Sb + sb);
    f.p8 = *(const s16x8*)(Sb + sb + SVEC);
    f.y8 = *(const s16x8*)(Sb + sb + 2 * SVEC);
    f.z8 = *(const s16x8*)(Sb + sb + 3 * SVEC);
    if (LOADUV) {
        f.u8 = *(const s16x8*)(uv + ub);
        f.v8 = *(const s16x8*)(uv + ub + SVEC);
    } else {
        f.u8 = (s16x8){0,0,0,0,0,0,0,0};
        f.v8 = (s16x8){0,0,0,0,0,0,0,0};
    }
}

// math identical to the verified k_fbs; writes Sb in place and writes the
// interleaved k'=4j+b slab into the LDS A-buffer (XOR-swizzled 16B chunks:
// chunk ^ (row&7), same function applied on the MFMA read side).
__device__ __forceinline__ void fbs_finish(ushort* __restrict__ Sb, size_t sb,
                                           ushort* __restrict__ buf,
                                           int frow, int fjg,
                                           float an, float al,
                                           FbsReg& f, float& r, float& d) {
    s16x8 xo, po, yo, zo;
    const ushort* X = (const ushort*)&f.x8; const ushort* P = (const ushort*)&f.p8;
    const ushort* Y = (const ushort*)&f.y8; const ushort* Z = (const ushort*)&f.z8;
    const ushort* U = (const ushort*)&f.u8; const ushort* V = (const ushort*)&f.v8;
    ushort* XO = (ushort*)&xo; ushort* PO = (ushort*)&po;
    ushort* YO = (ushort*)&yo; ushort* ZO = (ushort*)&zo;
    #pragma unroll
    for (int cc = 0; cc < 8; ++cc) {
        float x = bf2f(X[cc]), p = bf2f(P[cc]);
        float yv = bf2f(Y[cc]), zv = bf2f(Z[cc]);
        float u = al * bf2f(U[cc]), v = al * bf2f(V[cc]);
        float y  = x + an * (yv - x) + u;
        float dz = an * (zv - p);
        float z  = x + an * (p - x) + dz + u + v;
        float zm = z - y;
        float t  = fabsf(zm) - 0.1f;
        float pr = (t > 0.f) ? copysignf(t, zm) : 0.f;
        float xn = x + (pr - z) + dz;
        XO[cc] = f2bf(xn); PO[cc] = f2bf(pr); YO[cc] = f2bf(y); ZO[cc] = f2bf(z);
        float e1 = pr - y; r += e1 * e1;
        float e2 = xn - z; d += e2 * e2;
    }
    *(s16x8*)(Sb + sb)            = xo;
    *(s16x8*)(Sb + sb + SVEC)     = po;
    *(s16x8*)(Sb + sb + 2 * SVEC) = yo;
    *(s16x8*)(Sb + sb + 3 * SVEC) = zo;
    #pragma unroll
    for (int cc = 0; cc < 4; ++cc) {
        s16x8 w; ushort* W = (ushort*)&w;
        #pragma unroll
        for (int t = 0; t < 2; ++t) {
            int jj = cc * 2 + t;
            W[t*4+0] = XO[jj]; W[t*4+1] = PO[jj];
            W[t*4+2] = YO[jj]; W[t*4+3] = ZO[jj];
        }
        int ch = (4 * fjg + cc) ^ (frow & 7);
        *(s16x8*)&buf[frow * 256 + ch * 8] = w;
    }
}

// step-19 variant: p_out f32 direct, r only, no Sb/A writes (x,p,y,z,uv dead
// after this step; only pr and the residual survive).
__device__ __forceinline__ void fin_last(float* __restrict__ dst,
                                         float an, float al,
                                         FbsReg& f, float& r) {
    float prf[8];
    const ushort* X = (const ushort*)&f.x8; const ushort* P = (const ushort*)&f.p8;
    const ushort* Y = (const ushort*)&f.y8; const ushort* Z = (const ushort*)&f.z8;
    const ushort* U = (const ushort*)&f.u8; const ushort* V = (const ushort*)&f.v8;
    #pragma unroll
    for (int cc = 0; cc < 8; ++cc) {
        float x = bf2f(X[cc]), p = bf2f(P[cc]);
        float yv = bf2f(Y[cc]), zv = bf2f(Z[cc]);
        float u = al * bf2f(U[cc]), v = al * bf2f(V[cc]);
        float y  = x + an * (yv - x) + u;
        float dz = an * (zv - p);
        float z  = x + an * (p - x) + dz + u + v;
        float zm = z - y;
        float t  = fabsf(zm) - 0.1f;
        float pr = (t > 0.f) ? copysignf(t, zm) : 0.f;
        prf[cc] = pr;
        float e1 = pr - y; r += e1 * e1;
    }
    *(float4*)(dst)     = make_float4(prf[0], prf[1], prf[2], prf[3]);
    *(float4*)(dst + 4) = make_float4(prf[4], prf[5], prf[6], prf[7]);
}

// ---------- fused per-step kernel (R11 structure + depth-2 FBS pipeline) -----
// 1 block = 64 samples, 512 threads (8 waves). grid = 256 = 1 block/CU.
// MODE: 0 = first step (skip uv reads), 1 = middle, 2 = last (FBS-only,
// writes p_out f32 directly, no GEMMs / Sb writeback / barriers).
// Depth-2 FBS pipeline: two FbsReg buffers; chunk c+2's Sb/uv loads are
// issued at iteration c, consumed by fbs_finish at iteration c+1 -- the
// load->use distance on the DOMINANT HBM stream doubles vs R11.
template<int MODE>
__global__ __launch_bounds__(512, 2) void k_step(
    ushort* __restrict__ Sb, ushort* __restrict__ uv,
    const ushort* __restrict__ Wf1, const ushort* __restrict__ Wf2,
    const ushort* __restrict__ Wf3,
    const float* __restrict__ b1v, const float* __restrict__ b2v,
    const float* __restrict__ b3v,
    const float* __restrict__ redprev, float* __restrict__ redcur,
    float an, float* __restrict__ pout) {
    __shared__ ushort As[2][64 * 256];        // 2 x 32 KB: A dbuf, then h1/h2
    const int tid  = threadIdx.x;
    const int wave = tid >> 6, lane = tid & 63;
    const int lm = lane & 15, quad = lane >> 4;
    const int sample0 = blockIdx.x * 64;
    const int frow = tid >> 3, fjg = tid & 7;   // FBS: 64 rows x 8 jgroups

    const s16x8* Wf1v = (const s16x8*)Wf1;
    const s16x8* Wf2v = (const s16x8*)Wf2;
    const s16x8* Wf3v = (const s16x8*)Wf3;

    // ---- inline alpha (same reduction as verified kernels) ----
    float av = (lane < 32) ? redprev[512 + lane * 16]
                           : redprev[1024 + (lane - 32) * 16];
    #pragma unroll
    for (int off = 16; off > 0; off >>= 1) av += __shfl_down(av, off);
    const float dsum = __shfl(av, 0), qsum = __shfl(av, 32);
    const float al = sqrtf(fminf(0.99f * fmaxf(dsum, 0.f) /
                                 (1.5f * qsum + 1e-12f), 1.f));

    const size_t srow = (size_t)(sample0 + frow) * INF  + fjg * 8;
    const size_t urow = (size_t)(sample0 + frow) * OUTF + fjg * 8;

    float r = 0.f, d = 0.f;

    if constexpr (MODE == 2) {
        // ---- step 19: FBS-only, p_out f32 direct, r only, no barriers ----
        float* prow = pout + (size_t)(sample0 + frow) * SVEC + fjg * 8;
        FbsReg g0, g1;
        fbs_load<true>(Sb, uv, srow,      urow,      g0);
        fbs_load<true>(Sb, uv, srow + 64, urow + 64, g1);
        fin_last(prow,       an, al, g0, r);
        fbs_load<true>(Sb, uv, srow + 128, urow + 128, g0);
        fin_last(prow + 64,  an, al, g1, r);
        fbs_load<true>(Sb, uv, srow + 192, urow + 192, g1);
        fin_last(prow + 128, an, al, g0, r);
        fbs_load<true>(Sb, uv, srow + 256, urow + 256, g0);
        fin_last(prow + 192, an, al, g1, r);
        fbs_load<true>(Sb, uv, srow + 320, urow + 320, g1);
        fin_last(prow + 256, an, al, g0, r);
        fbs_load<true>(Sb, uv, srow + 384, urow + 384, g0);
        fin_last(prow + 320, an, al, g1, r);
        fbs_load<true>(Sb, uv, srow + 448, urow + 448, g1);
        fin_last(prow + 384, an, al, g0, r);
        fbs_load<true>(Sb, uv, srow + 512, urow + 512, g0);
        fin_last(prow + 448, an, al, g1, r);
        fin_last(prow + 512, an, al, g0, r);
        #pragma unroll
        for (int off = 32; off > 0; off >>= 1) r += __shfl_down(r, off);
        if (lane == 0)
            atomicAdd(&redcur[(((blockIdx.x << 3) | wave) & 31) * 16], r);
        return;
    }

    constexpr bool LUV = (MODE != 0);
    FbsReg g0, g1;
    s16x8 b1[4][2];

    // prologue: issue chunk0 AND chunk1 loads, then finish chunk0 (depth-2)
    fbs_load<LUV>(Sb, uv, srow,      urow,      g0);
    fbs_load<LUV>(Sb, uv, srow + 64, urow + 64, g1);
    fbs_finish(Sb, srow, As[0], frow, fjg, an, al, g0, r, d);
    #pragma unroll
    for (int t = 0; t < 3; ++t)
        #pragma unroll
        for (int j = 0; j < 2; ++j)
            b1[t][j] = Wf1v[((wave * 2 + j) * 72 + t) * 64 + lane];
    bar_lgkm();

    f32x4 acc[4][2];
    #pragma unroll
    for (int i = 0; i < 4; ++i)
        #pragma unroll
        for (int j = 0; j < 2; ++j) acc[i][j] = (f32x4){0.f, 0.f, 0.f, 0.f};

    #pragma unroll
    for (int c = 0; c < 9; ++c) {
        // issue chunk c+2 loads into the buffer freed by finish(c) last iter
        if (c + 2 <= 8) {
            FbsReg& gld = (c & 1) ? g1 : g0;          // g[c%2], static per iter
            fbs_load<LUV>(Sb, uv, srow + (size_t)(c + 2) * 64,
                          urow + (size_t)(c + 2) * 64, gld);
        }
        const ushort* Ab = As[c & 1];
        #pragma unroll
        for (int kk = 0; kk < 8; ++kk) {
            // distance-3 prefetch; c*8 % 4 == 0 so slot = (kk+3)&3 is static
            if (c < 8 || kk < 5) {
                const int tg3 = c * 8 + kk + 3;
                #pragma unroll
                for (int j = 0; j < 2; ++j)
                    b1[(kk + 3) & 3][j] =
                        Wf1v[((wave * 2 + j) * 72 + tg3) * 64 + lane];
            }
            s16x8 af[4];
            #pragma unroll
            for (int i = 0; i < 4; ++i)
                af[i] = *(const s16x8*)&Ab[(i * 16 + lm) * 256 +
                         ((((kk << 2) + quad) ^ (lm & 7)) << 3)];
            #pragma unroll
            for (int i = 0; i < 4; ++i)
                #pragma unroll
                for (int j = 0; j < 2; ++j)
                    acc[i][j] = __builtin_amdgcn_mfma_f32_16x16x32_bf16(
                        af[i], b1[kk & 3][j], acc[i][j], 0, 0, 0);
        }
        if (c < 8) {
            FbsReg& gfin = (c & 1) ? g0 : g1;         // g[(c+1)%2], chunk c+1
            fbs_finish(Sb, srow + (size_t)(c + 1) * 64, As[(c + 1) & 1],
                       frow, fjg, an, al, gfin, r, d);
            bar_lgkm();  // no barrier after chunk 8 (As[1] reads were fenced
                         // at the chunk-7 barrier)
        }
    }

    // ---- r/d reductions ----
    #pragma unroll
    for (int off = 32; off > 0; off >>= 1) {
        r += __shfl_down(r, off);
        d += __shfl_down(d, off);
    }
    if (lane == 0) {
        int bk = ((blockIdx.x << 3) | wave) & 31;
        atomicAdd(&redcur[bk * 16],       r);
        atomicAdd(&redcur[512 + bk * 16], d);
    }

    // ---- h1 = relu(acc + b1) staged in LDS ----
    ushort* h1l = As[1];
    float bb1[2];
    #pragma unroll
    for (int j = 0; j < 2; ++j) bb1[j] = b1v[wave * 32 + j * 16 + lm];
    #pragma unroll
    for (int i = 0; i < 4; ++i)
        #pragma unroll
        for (int j = 0; j < 2; ++j)
            #pragma unroll
            for (int rr = 0; rr < 4; ++rr) {
                int row = i * 16 + quad * 4 + rr;
                int col = wave * 32 + j * 16 + lm;
                float cv = fmaxf(acc[i][j][rr] + bb1[j], 0.f);
                h1l[row * 256 + ((((col >> 3) ^ (row & 7)) << 3) | (col & 7))] =
                    f2bf(cv);
            }
    // preload GEMM2 kk=0,1,2 B-frags (global, no LDS dependency)
    s16x8 b2[4][2];
    #pragma unroll
    for (int t = 0; t < 3; ++t)
        #pragma unroll
        for (int j = 0; j < 2; ++j)
            b2[t][j] = Wf2v[((wave * 2 + j) * 8 + t) * 64 + lane];
    bar_lgkm();

    // ---- GEMM2: h2 = relu(h1 @ W2 + b2), K = 256 ----
    f32x4 a2[4][2];
    #pragma unroll
    for (int i = 0; i < 4; ++i)
        #pragma unroll
        for (int j = 0; j < 2; ++j) a2[i][j] = (f32x4){0.f, 0.f, 0.f, 0.f};
    #pragma unroll
    for (int kk = 0; kk < 8; ++kk) {
        if (kk < 5) {
            #pragma unroll
            for (int j = 0; j < 2; ++j)
                b2[(kk + 3) & 3][j] =
                    Wf2v[((wave * 2 + j) * 8 + kk + 3) * 64 + lane];
        }
        s16x8 af[4];
        #pragma unroll
        for (int i = 0; i < 4; ++i)
            af[i] = *(const s16x8*)&h1l[(i * 16 + lm) * 256 +
                     ((((kk << 2) + quad) ^ (lm & 7)) << 3)];
        #pragma unroll
        for (int i = 0; i < 4; ++i)
            #pragma unroll
            for (int j = 0; j < 2; ++j)
                a2[i][j] = __builtin_amdgcn_mfma_f32_16x16x32_bf16(
                    af[i], b2[kk & 3][j], a2[i][j], 0, 0, 0);
    }
    ushort* h2l = As[0];
    float bb2[2];
    #pragma unroll
    for (int j = 0; j < 2; ++j) bb2[j] = b2v[wave * 32 + j * 16 + lm];
    #pragma unroll
    for (int i = 0; i < 4; ++i)
        #pragma unroll
        for (int j = 0; j < 2; ++j)
            #pragma unroll
            for (int rr = 0; rr < 4; ++rr) {
                int row = i * 16 + quad * 4 + rr;
                int col = wave * 32 + j * 16 + lm;
                float cv = fmaxf(a2[i][j][rr] + bb2[j], 0.f);
                h2l[row * 256 + ((((col >> 3) ^ (row & 7)) << 3) | (col & 7))] =
                    f2bf(cv);
            }
    // preload GEMM3 t=0,1,2 B-frags
    s16x8 b3[4][3];
    #pragma unroll
    for (int t = 0; t < 3; ++t)
        #pragma unroll
        for (int jj = 0; jj < 3; ++jj)
            b3[t][jj] = Wf3v[((wave * 9 + jj) * 8 + t) * 64 + lane];
    bar_lgkm();

    // ---- GEMM3: out = h2 @ W3 + b3 (no relu), 144 cols/wave, 3 passes ----
    float q = 0.f;
    f32x4 a3[3][4];
    #pragma unroll
    for (int t = 0; t < 24; ++t) {
        const int p = t >> 3, kk = t & 7;
        if (t < 21) {                             // distance-3, crosses passes
            const int tp = (t + 3) >> 3, tk = (t + 3) & 7;
            #pragma unroll
            for (int jj = 0; jj < 3; ++jj)
                b3[(t + 3) & 3][jj] =
                    Wf3v[((wave * 9 + tp * 3 + jj) * 8 + tk) * 64 + lane];
        }
        if (kk == 0) {
            #pragma unroll
            for (int jj = 0; jj < 3; ++jj)
                #pragma unroll
                for (int i = 0; i < 4; ++i) a3[jj][i] = (f32x4){0.f,0.f,0.f,0.f};
        }
        s16x8 af[4];
        #pragma unroll
        for (int i = 0; i < 4; ++i)
            af[i] = *(const s16x8*)&h2l[(i * 16 + lm) * 256 +
                     ((((kk << 2) + quad) ^ (lm & 7)) << 3)];
        #pragma unroll
        for (int jj = 0; jj < 3; ++jj)
            #pragma unroll
            for (int i = 0; i < 4; ++i)
                a3[jj][i] = __builtin_amdgcn_mfma_f32_16x16x32_bf16(
                    af[i], b3[t & 3][jj], a3[jj][i], 0, 0, 0);
        if (kk == 7) {                            // epilogue for pass p
            #pragma unroll
            for (int jj = 0; jj < 3; ++jj) {
                int col = (wave * 9 + p * 3 + jj) * 16 + lm;
                float bb = b3v[col];
                #pragma unroll
                for (int i = 0; i < 4; ++i)
                    #pragma unroll
                    for (int rr = 0; rr < 4; ++rr) {
                        int row = i * 16 + quad * 4 + rr;
                        float cv = a3[jj][i][rr] + bb;
                        q += cv * cv;
                        uv[(size_t)(sample0 + row) * OUTF + col] = f2bf(cv);
                    }
            }
        }
    }
    #pragma unroll
    for (int off = 32; off > 0; off >>= 1) q += __shfl_down(q, off);
    if (lane == 0)
        atomicAdd(&redcur[1024 + (((blockIdx.x << 3) | wave) & 31) * 16], q);
}

// ---------- residuals only (p_out written by k_step<2>) ----------------------
__global__ __launch_bounds__(64) void k_res(const float* __restrict__ red,
                                            float* __restrict__ res_out) {
    int t = threadIdx.x;
    if (t >= TS) return;
    const float* rb = red + (size_t)(t + 1) * RSL;
    float s = 0.f;
    #pragma unroll
    for (int c = 0; c < 32; ++c) s += rb[c * 16];
    res_out[t] = sqrtf(s + 1e-12f);
}

extern "C" void kernel_launch(void* const* d_in, const int* in_sizes, int n_in,
                              void* d_out, int out_size, void* d_ws, size_t ws_size,
                              hipStream_t stream) {
    const float* noisy = (const float*)d_in[0];
    const float* W1 = (const float*)d_in[1];
    const float* b1 = (const float*)d_in[2];
    const float* W2 = (const float*)d_in[3];
    const float* b2 = (const float*)d_in[4];
    const float* W3 = (const float*)d_in[5];
    const float* b3 = (const float*)d_in[6];
    const int B = in_sizes[0] / 64;   // 16384

    // workspace layout (~115 MB)
    ushort* Sb  = (ushort*)d_ws;                        // [B,2304] bf16
    ushort* uv  = Sb + (size_t)B * INF;                 // [B,1152] bf16
    ushort* Wf1 = uv + (size_t)B * OUTF;                // 16*72*512 frag-linear
    ushort* Wf2 = Wf1 + (size_t)HID * INF;              // 16*8*512
    ushort* Wf3 = Wf2 + (size_t)HID * HID;              // 72*8*512
    float*  red = (float*)((((uintptr_t)(Wf3 + (size_t)OUTF * HID)) + 63) &
                           ~(uintptr_t)63);

    float* p_out   = (float*)d_out;                     // [B,576]
    float* res_out = p_out + (size_t)B * SVEC;          // [20]

    const int tot8S = B * 288;   // s16x8 slots in Sb

    k_init<<<(tot8S + 255) / 256, 256, 0, stream>>>(Sb, (const float4*)noisy, tot8S);
    k_zero<<<(21 * RSL + 127) / 128, 128, 0, stream>>>(red, 21 * RSL);
    // uv is NOT zeroed: step 0 uses MODE=0 (uv never read there).
    k_wf<<<(HID * INF + 255) / 256, 256, 0, stream>>>(W1, Wf1, 72, HID, 1, HID * INF);
    k_wf<<<(HID * HID + 255) / 256, 256, 0, stream>>>(W2, Wf2, 8, HID, 0, HID * HID);
    k_wf<<<(OUTF * HID + 255) / 256, 256, 0, stream>>>(W3, Wf3, 8, OUTF, 0, OUTF * HID);

    k_step<0><<<B / 64, 512, 0, stream>>>(
        Sb, uv, Wf1, Wf2, Wf3, b1, b2, b3,
        red, red + RSL, 0.0f, p_out);
    for (int n = 1; n < TS - 1; ++n) {
        float an = (float)n / ((float)n + 3.0f);
        k_step<1><<<B / 64, 512, 0, stream>>>(
            Sb, uv, Wf1, Wf2, Wf3, b1, b2, b3,
            red + (size_t)n * RSL, red + (size_t)(n + 1) * RSL, an, p_out);
    }
    {
        float an = (float)(TS - 1) / ((float)(TS - 1) + 3.0f);
        k_step<2><<<B / 64, 512, 0, stream>>>(
            Sb, uv, Wf1, Wf2, Wf3, b1, b2, b3,
            red + (size_t)(TS - 1) * RSL, red + (size_t)TS * RSL, an, p_out);
    }
    k_res<<<1, 64, 0, stream>>>(red, res_out);
}